// Round 2
// baseline (2149.482 us; speedup 1.0000x reference)
//
#include <hip/hip_runtime.h>

constexpr int HI = 256, WI = 256;   // reg_feat spatial
constexpr int HO = 512, WO = 512;   // upsampled spatial
constexpr int CI = 32;              // feat channels
constexpr int CK = 49;              // 7x7 unfold channels

// ws layout (float offsets)
constexpr size_t OFF_WTR = 0;                       // [16 taps][32 i][32 o] = 16384
constexpr size_t OFF_W1R = 16384;                   // [32 i][7 t][49 o] = 10976 (pad to 11008)
constexpr size_t OFF_W2R = 16384 + 11008;           // [49 i][7 t][49 o] = 16807
constexpr size_t OFF_F0  = 49152;                   // 32*512*512
constexpr size_t OFF_F1  = OFF_F0 + (size_t)CI * HO * WO;

// ---------------------------------------------------------------------------
// Repack weights so that, for fixed (tap/i/t), the o-channels are contiguous
// and the load index is wave-uniform -> compiler emits s_load (scalar pipe).
// ---------------------------------------------------------------------------
__global__ void repack(const float* __restrict__ wt, const float* __restrict__ w1,
                       const float* __restrict__ w2, float* __restrict__ wtr,
                       float* __restrict__ w1r, float* __restrict__ w2r)
{
    const int j = blockIdx.x * 256 + threadIdx.x;
    if (j < 16384) {                       // wt: [i][o][kh][kw] -> wtr[tap][i*32+o]
        const int io = j >> 4, tap = j & 15;
        wtr[tap * 1024 + io] = wt[j];
    }
    if (j < CK * CI * 7) {                 // w1: [o][i][t] -> w1r[(i*7+t)*49+o]
        const int o = j / 224, r = j % 224;
        w1r[r * 49 + o] = w1[j];
    }
    if (j < CK * CK * 7) {                 // w2: [o][i][t] -> w2r[(i*7+t)*49+o]
        const int o = j / 343, r = j % 343;
        w2r[r * 49 + o] = w2[j];
    }
}

// ---------------------------------------------------------------------------
// Stage A: ConvTranspose2d(32,32,4,s=2,p=1).
// y[o,oh,ow] = bt[o] + sum_{i,kh,kw} x[i,(oh+1-kh)/2,(ow+1-kw)/2] * wt[i,o,kh,kw]
// (indices valid only when divisions are exact and in range).
// Block = one output row; thread = adjacent pixel pair (2u, 2u+1) so the
// kw-parity is a compile-time constant per accumulator.
// ---------------------------------------------------------------------------
__global__ __launch_bounds__(256, 2)
void kA(const float* __restrict__ x, const float* __restrict__ wtr,
        const float* __restrict__ bt, float* __restrict__ f0)
{
    const int u   = threadIdx.x;          // pixels ow = 2u, 2u+1
    const int oh  = blockIdx.x;
    const int kh0 = (oh & 1) ? 0 : 1;     // kh parity matching oh
    const int ihA = (oh + 1 - kh0) >> 1;  // row for kh = kh0
    const int ihB = ihA - 1;              // row for kh = kh0+2
    const bool vA = (unsigned)ihA < (unsigned)HI;
    const bool vB = (unsigned)ihB < (unsigned)HI;
    const int tA  = kh0 * 4;              // tap base for kh0
    const int tB  = tA + 8;               // tap base for kh0+2

    float acc0[32], acc1[32];
    #pragma unroll
    for (int o = 0; o < 32; ++o) { acc0[o] = 0.f; acc1[o] = 0.f; }

    for (int i = 0; i < CI; ++i) {
        const float* xi = x + i * (HI * WI);
        const float* rA = xi + ihA * WI;
        const float* rB = xi + ihB * WI;
        const float a0 = (vA && u >= 1)  ? rA[u - 1] : 0.f;
        const float a1 =  vA             ? rA[u]     : 0.f;
        const float a2 = (vA && u < 255) ? rA[u + 1] : 0.f;
        const float c0 = (vB && u >= 1)  ? rB[u - 1] : 0.f;
        const float c1 =  vB             ? rB[u]     : 0.f;
        const float c2 = (vB && u < 255) ? rB[u + 1] : 0.f;
        const float* wb = wtr + i * 32;   // + tap*1024 + o
        #pragma unroll
        for (int o = 0; o < 32; ++o) {
            const float wA0 = wb[(tA + 0) * 1024 + o];
            const float wA1 = wb[(tA + 1) * 1024 + o];
            const float wA2 = wb[(tA + 2) * 1024 + o];
            const float wA3 = wb[(tA + 3) * 1024 + o];
            const float wB0 = wb[(tB + 0) * 1024 + o];
            const float wB1 = wb[(tB + 1) * 1024 + o];
            const float wB2 = wb[(tB + 2) * 1024 + o];
            const float wB3 = wb[(tB + 3) * 1024 + o];
            // even pixel (2u): kw in {1,3} -> iw {u, u-1}
            acc0[o] += a1 * wA1 + a0 * wA3 + c1 * wB1 + c0 * wB3;
            // odd pixel (2u+1): kw in {0,2} -> iw {u+1, u}
            acc1[o] += a2 * wA0 + a1 * wA2 + c2 * wB0 + c1 * wB2;
        }
    }
    #pragma unroll
    for (int o = 0; o < 32; ++o) {
        const float bv = bt[o];
        float2 v = make_float2(acc0[o] + bv, acc1[o] + bv);
        *reinterpret_cast<float2*>(&f0[((size_t)o * HO + oh) * WO + 2 * u]) = v;
    }
}

// ---------------------------------------------------------------------------
// Stage B: 7x1 vertical conv, 32->49. Thread = 1 pixel, all 49 out channels.
// Weights via uniform-index global reads (scalar pipe), no LDS.
// ---------------------------------------------------------------------------
__global__ __launch_bounds__(256, 4)
void kB(const float* __restrict__ f0, const float* __restrict__ w1r,
        const float* __restrict__ b1, float* __restrict__ f1)
{
    const int tid = threadIdx.x;
    const int h = blockIdx.x >> 1;
    const int w = ((blockIdx.x & 1) << 8) + tid;

    float acc[CK];
    #pragma unroll
    for (int o = 0; o < CK; ++o) acc[o] = 0.f;

    for (int i = 0; i < CI; ++i) {
        const float* xi = f0 + (size_t)i * (HO * WO) + w;
        float xw[7];
        #pragma unroll
        for (int t = 0; t < 7; ++t) {
            const int hh = h + t - 3;
            xw[t] = ((unsigned)hh < (unsigned)HO) ? xi[hh * WO] : 0.f;
        }
        const float* wrow = w1r + i * (7 * 49);
        #pragma unroll
        for (int t = 0; t < 7; ++t) {
            #pragma unroll
            for (int o = 0; o < CK; ++o)
                acc[o] += wrow[t * 49 + o] * xw[t];
        }
    }
    #pragma unroll
    for (int o = 0; o < CK; ++o)
        f1[((size_t)o * HO + h) * WO + w] = acc[o] + b1[o];
}

// ---------------------------------------------------------------------------
// Stage C: 1x7 horizontal conv 49->49 + softmax(-(f2^2)) + unfold-weighted
// flow average. Thread = 1 pixel.
// ---------------------------------------------------------------------------
__global__ __launch_bounds__(256, 4)
void kC(const float* __restrict__ f1, const float* __restrict__ w2r,
        const float* __restrict__ b2, const float* __restrict__ flow,
        float* __restrict__ out)
{
    const int tid = threadIdx.x;
    const int h = blockIdx.x >> 1;
    const int w = ((blockIdx.x & 1) << 8) + tid;

    float s[CK];
    #pragma unroll
    for (int o = 0; o < CK; ++o) s[o] = 0.f;

    for (int i = 0; i < CK; ++i) {
        const float* xi = f1 + ((size_t)i * HO + h) * WO;
        float xw[7];
        #pragma unroll
        for (int t = 0; t < 7; ++t) {
            const int ww = w + t - 3;
            xw[t] = ((unsigned)ww < (unsigned)WO) ? xi[ww] : 0.f;
        }
        const float* wrow = w2r + i * (7 * 49);
        #pragma unroll
        for (int t = 0; t < 7; ++t) {
            #pragma unroll
            for (int o = 0; o < CK; ++o)
                s[o] += wrow[t * 49 + o] * xw[t];
        }
    }

    // epilogue: f2 = s+b2; sq = f2^2; dist = exp(min(sq)-sq); weighted flow avg
    #pragma unroll
    for (int o = 0; o < CK; ++o) {
        const float v = s[o] + b2[o];
        s[o] = v * v;
    }
    float m = s[0];
    #pragma unroll
    for (int o = 1; o < CK; ++o) m = fminf(m, s[o]);

    const float* fx = flow;
    const float* fy = flow + (size_t)HO * WO;
    float div = 0.f, sx = 0.f, sy = 0.f;
    #pragma unroll
    for (int ki = 0; ki < 7; ++ki) {
        const int hh = h + ki - 3;
        const bool vh = ((unsigned)hh < (unsigned)HO);
        const float* fxr = fx + (size_t)hh * WO;
        const float* fyr = fy + (size_t)hh * WO;
        #pragma unroll
        for (int kj = 0; kj < 7; ++kj) {
            const int o  = ki * 7 + kj;
            const int ww = w + kj - 3;
            const float d = __expf(m - s[o]);
            div += d;
            const bool v = vh && ((unsigned)ww < (unsigned)WO);
            sx += d * (v ? fxr[ww] : 0.f);
            sy += d * (v ? fyr[ww] : 0.f);
        }
    }
    out[(size_t)h * WO + w]                    = sx / div;
    out[(size_t)HO * WO + (size_t)h * WO + w]  = sy / div;
}

// ---------------------------------------------------------------------------
extern "C" void kernel_launch(void* const* d_in, const int* in_sizes, int n_in,
                              void* d_out, int out_size, void* d_ws, size_t ws_size,
                              hipStream_t stream) {
    const float* reg_feat = (const float*)d_in[0];
    const float* flow     = (const float*)d_in[1];
    const float* wt       = (const float*)d_in[2];
    const float* bt       = (const float*)d_in[3];
    const float* w1       = (const float*)d_in[4];
    const float* b1       = (const float*)d_in[5];
    const float* w2       = (const float*)d_in[6];
    const float* b2       = (const float*)d_in[7];
    float* out = (float*)d_out;
    (void)in_sizes; (void)n_in; (void)out_size; (void)ws_size;

    float* ws  = (float*)d_ws;
    float* wtr = ws + OFF_WTR;
    float* w1r = ws + OFF_W1R;
    float* w2r = ws + OFF_W2R;
    float* f0  = ws + OFF_F0;
    float* f1  = ws + OFF_F1;

    repack<<<66, 256, 0, stream>>>(wt, w1, w2, wtr, w1r, w2r);

    for (int b = 0; b < 4; ++b) {
        const float* xb  = reg_feat + (size_t)b * CI * HI * WI;
        const float* flb = flow     + (size_t)b * 2 * HO * WO;
        float*       ob  = out      + (size_t)b * 2 * HO * WO;
        kA<<<512,  256, 0, stream>>>(xb, wtr, bt, f0);
        kB<<<1024, 256, 0, stream>>>(f0, w1r, b1, f1);
        kC<<<1024, 256, 0, stream>>>(f1, w2r, b2, flb, ob);
    }
}

// Round 3
// 1015.427 us; speedup vs baseline: 2.1168x; 2.1168x over previous
//
#include <hip/hip_runtime.h>

constexpr int HI = 256, WI = 256;   // reg_feat spatial
constexpr int HO = 512, WO = 512;   // upsampled spatial
constexpr int CI = 32;              // feat channels
constexpr int CK = 49;              // 7x7 unfold channels

// ---- ws layout (float offsets) --------------------------------------------
constexpr size_t OFF_WPC = 0;        // packed w2 frags: 13*2*4*64 uint4 = 26624 f32
constexpr size_t OFF_B2P = 26624;    // padded b2 [64]
constexpr size_t OFF_F0  = 32768;    // f0 [32][512][512] f32  (flowp aliases this)
constexpr size_t OFF_F1  = OFF_F0 + (size_t)CI * HO * WO;   // f1 [49][512][512] f32

constexpr int FP_W = 518;            // padded flow row (512 + 3 + 3)

using bf16x8 = __attribute__((ext_vector_type(8))) short;
using f32x4  = __attribute__((ext_vector_type(4))) float;

__device__ inline unsigned bf_rne(float x) {           // fp32 -> bf16 bits (RNE)
    unsigned u = __float_as_uint(x);
    return (u + 0x7FFFu + ((u >> 16) & 1u)) >> 16;
}

union FragU { uint4 q; bf16x8 v; unsigned u[4]; };

// ---------------------------------------------------------------------------
// Stage A: ConvTranspose2d(32,32,4,s=2,p=1)  [R0 version, known-good]
// ---------------------------------------------------------------------------
__global__ __launch_bounds__(256, 2)
void kA(const float* __restrict__ x, const float* __restrict__ wt,
        const float* __restrict__ bt, float* __restrict__ f0)
{
    __shared__ float wl[16 * 1024];  // [tap=kh*4+kw][i][o]
    const int tid = threadIdx.x;
    for (int j = tid; j < 4096; j += 256) {
        const int r = j >> 2, tq = j & 3;       // r = i*32+o
        const float4 v = reinterpret_cast<const float4*>(wt)[j];
        wl[(4 * tq + 0) * 1024 + r] = v.x;
        wl[(4 * tq + 1) * 1024 + r] = v.y;
        wl[(4 * tq + 2) * 1024 + r] = v.z;
        wl[(4 * tq + 3) * 1024 + r] = v.w;
    }
    __syncthreads();

    const int oh  = blockIdx.x;
    const int kh0 = (oh & 1) ? 0 : 1;
    const int ow0 = tid;
    const int kw0 = (ow0 & 1) ? 0 : 1;

    float acc0[32], acc1[32];
    #pragma unroll
    for (int o = 0; o < 32; ++o) { acc0[o] = 0.f; acc1[o] = 0.f; }

    for (int i = 0; i < CI; ++i) {
        const float* xi = x + i * (HI * WI);
        #pragma unroll
        for (int a = 0; a < 2; ++a) {
            const int kh = kh0 + 2 * a;
            const int ih = (oh + 1 - kh) >> 1;
            const bool vh = ((unsigned)ih < (unsigned)HI);
            const float* xr = xi + ih * WI;
            #pragma unroll
            for (int d = 0; d < 2; ++d) {
                const int kw  = kw0 + 2 * d;
                const int iw0 = (ow0 + 1 - kw) >> 1;
                const int iw1 = iw0 + 128;
                const float xv0 = (vh && (unsigned)iw0 < (unsigned)WI) ? xr[iw0] : 0.f;
                const float xv1 = (vh && (unsigned)iw1 < (unsigned)WI) ? xr[iw1] : 0.f;
                const float* wp = wl + (kh * 4 + kw) * 1024 + i * 32;
                #pragma unroll
                for (int o = 0; o < 32; ++o) {
                    const float wv = wp[o];
                    acc0[o] += xv0 * wv;
                    acc1[o] += xv1 * wv;
                }
            }
        }
    }
    #pragma unroll
    for (int o = 0; o < 32; ++o) {
        const float bv = bt[o];
        f0[(o * HO + oh) * WO + ow0]       = acc0[o] + bv;
        f0[(o * HO + oh) * WO + ow0 + 256] = acc1[o] + bv;
    }
}

// ---------------------------------------------------------------------------
// Stage B: 7x1 vertical conv 32->49  [R0 version, known-good]
// ---------------------------------------------------------------------------
__global__ __launch_bounds__(256, 2)
void kB(const float* __restrict__ f0, const float* __restrict__ w1,
        const float* __restrict__ b1, float* __restrict__ f1)
{
    __shared__ float wl[32 * 7 * 52];
    const int tid = threadIdx.x;
    for (int j = tid; j < CK * CI * 7; j += 256) {
        const int o = j / 224, r = j % 224;
        const int i = r / 7, t = r % 7;
        wl[(i * 7 + t) * 52 + o] = w1[j];
    }
    __syncthreads();

    const int lane = tid & 63;
    const int wv_  = tid >> 6;
    const int c    = ((blockIdx.x & 7) << 6) + lane;
    const int h0   = ((blockIdx.x >> 3) << 3) + wv_ * 2;

    float acc0[CK], acc1[CK];
    #pragma unroll
    for (int o = 0; o < CK; ++o) { acc0[o] = 0.f; acc1[o] = 0.f; }

    for (int i = 0; i < CI; ++i) {
        const float* xi = f0 + i * (HO * WO) + c;
        float xw[9];
        #pragma unroll
        for (int k = 0; k < 9; ++k) {
            const int hh = h0 + k - 3;
            xw[k] = ((unsigned)hh < (unsigned)HO) ? xi[hh * WO] : 0.f;
        }
        const float* wli = wl + i * (7 * 52);
        #pragma unroll
        for (int t = 0; t < 7; ++t) {
            const float* wrow = wli + t * 52;
            #pragma unroll
            for (int o = 0; o < CK; ++o) {
                const float wv = wrow[o];
                acc0[o] += wv * xw[t];
                acc1[o] += wv * xw[t + 1];
            }
        }
    }
    #pragma unroll
    for (int o = 0; o < CK; ++o) {
        const float bv = b1[o];
        f1[(o * HO + h0) * WO + c]     = acc0[o] + bv;
        f1[(o * HO + h0 + 1) * WO + c] = acc1[o] + bv;
    }
}

// ---------------------------------------------------------------------------
// repackC: build MFMA A-operand fragments of w2 (split bf16 hi/lo) + padded b2.
// k-enumeration (shared with kC's B reads): chunk c (0..12), lane-group g=lane>>4,
//   j=0..7 -> i = 4c+g, t = j (j==7 or i>=49 or o>=49 -> zero).
// Fragment store: wpC[((c*2+s)*4+mf)*64 + lane] = uint4 of 8 bf16 (k ascending).
// ---------------------------------------------------------------------------
__global__ void repackC(const float* __restrict__ w2, const float* __restrict__ b2,
                        uint4* __restrict__ wpC, float* __restrict__ b2p)
{
    const int j = blockIdx.x * 256 + threadIdx.x;
    if (j < 64) b2p[j] = (j < CK) ? b2[j] : 1e18f;
    if (j >= 13 * 2 * 4 * 64) return;
    const int c    = j >> 9;
    const int s    = (j >> 8) & 1;
    const int mf   = (j >> 6) & 3;
    const int lane = j & 63;
    const int o = mf * 16 + (lane & 15);
    const int i = 4 * c + (lane >> 4);

    unsigned b[8];
    #pragma unroll
    for (int t = 0; t < 8; ++t) {
        float v = 0.f;
        if (t < 7 && o < CK && i < CK) v = w2[o * 343 + i * 7 + t];
        const unsigned hi = bf_rne(v);
        if (s == 0) b[t] = hi;
        else {
            const float vh = __uint_as_float(hi << 16);
            b[t] = bf_rne(v - vh);
        }
    }
    uint4 q;
    q.x = (b[1] << 16) | b[0];
    q.y = (b[3] << 16) | b[2];
    q.z = (b[5] << 16) | b[4];
    q.w = (b[7] << 16) | b[6];
    wpC[((c * 2 + s) * 4 + mf) * 64 + lane] = q;
}

// ---------------------------------------------------------------------------
// kPad: flowp[p][hh][ww] = flow[p][hh-3][ww-3], zero outside. [2][518][518]
// ---------------------------------------------------------------------------
__global__ void kPad(const float* __restrict__ flow, float* __restrict__ flowp)
{
    const int idx = blockIdx.x * 256 + threadIdx.x;
    if (idx >= 2 * FP_W * FP_W) return;
    const int p  = idx / (FP_W * FP_W);
    const int q  = idx - p * (FP_W * FP_W);
    const int hh = q / FP_W;
    const int ww = q - hh * FP_W;
    float v = 0.f;
    const int hs = hh - 3, ws = ww - 3;
    if ((unsigned)hs < (unsigned)HO && (unsigned)ws < (unsigned)WO)
        v = flow[p * (HO * WO) + hs * WO + ws];
    flowp[idx] = v;
}

// ---------------------------------------------------------------------------
// kC: 1x7 conv 49->49 via split-bf16 MFMA (hi*hi + hi*lo + lo*hi), then
// per-pixel softmax(-(f2^2)) + unfold-weighted flow average.
// Block = 256 px of one row (4 waves x 64 px); wave tile = 64 px x 64 ch.
// M=channels (A=w2 frags from global), N=pixels (B=im2col from LDS row).
// ---------------------------------------------------------------------------
__global__ __launch_bounds__(256, 3)
void kC(const float* __restrict__ f1, const uint4* __restrict__ wpC,
        const float* __restrict__ b2p, const float* __restrict__ flowp,
        float* __restrict__ out)
{
    constexpr int LC = 264;                 // staged row length (256 + 3 + 3 + pad2)
    __shared__ unsigned L[CK * LC];         // packed (hi<<16|lo) bf16 pairs, 51.7 KB

    const int tid = threadIdx.x;
    const int h   = blockIdx.x >> 1;
    const int w0  = (blockIdx.x & 1) << 8;

    // stage f1 row h (49 ch, cols w0-3 .. w0+260) as split-bf16 packed u32
    for (int idx = tid; idx < CK * LC; idx += 256) {
        const int i = idx / LC;
        const int q = idx - i * LC;
        const int ww = w0 - 3 + q;
        float v = ((unsigned)ww < (unsigned)WO) ? f1[((size_t)i * HO + h) * WO + ww] : 0.f;
        const unsigned hi = bf_rne(v);
        const float vh = __uint_as_float(hi << 16);
        const unsigned lo = bf_rne(v - vh);
        L[idx] = (hi << 16) | lo;
    }
    __syncthreads();

    const int wv   = tid >> 6;
    const int lane = tid & 63;
    const int col  = lane & 15;
    const int g    = lane >> 4;
    const int pw   = wv * 64;               // wave's pixel base within block

    const int vb   = g * LC + pw + col;     // B vaddr for chunks 0..11 (i = 4c+g)
    const int vb12 = 48 * LC + pw + col;    // chunk 12: only g==0 (i=48) is live

    f32x4 acc[4][4];                        // [mf][nf]
    #pragma unroll
    for (int mf = 0; mf < 4; ++mf)
        #pragma unroll
        for (int nf = 0; nf < 4; ++nf)
            acc[mf][nf] = (f32x4){0.f, 0.f, 0.f, 0.f};

    #pragma unroll
    for (int c = 0; c < 13; ++c) {
        // B fragments (im2col activations) for 4 pixel-frags, hi & lo
        bf16x8 Bh[4], Bl[4];
        #pragma unroll
        for (int nf = 0; nf < 4; ++nf) {
            unsigned u[8];
            #pragma unroll
            for (int j = 0; j < 7; ++j) {
                const int off = (c < 12) ? (vb + c * (4 * LC) + nf * 16 + j)
                                         : (vb12 + nf * 16 + j);
                u[j] = L[off];
            }
            u[7] = 0u;
            FragU fh, fl;
            #pragma unroll
            for (int r = 0; r < 4; ++r) {
                fh.u[r] = (u[2 * r + 1] & 0xFFFF0000u) | (u[2 * r] >> 16);
                fl.u[r] = (u[2 * r + 1] << 16) | (u[2 * r] & 0xFFFFu);
            }
            Bh[nf] = fh.v;
            Bl[nf] = fl.v;
        }
        // A fragments (weights) and MFMAs
        #pragma unroll
        for (int mf = 0; mf < 4; ++mf) {
            FragU ah, al;
            ah.q = wpC[((c * 2 + 0) * 4 + mf) * 64 + lane];
            al.q = wpC[((c * 2 + 1) * 4 + mf) * 64 + lane];
            #pragma unroll
            for (int nf = 0; nf < 4; ++nf) {
                acc[mf][nf] = __builtin_amdgcn_mfma_f32_16x16x32_bf16(ah.v, Bh[nf], acc[mf][nf], 0, 0, 0);
                acc[mf][nf] = __builtin_amdgcn_mfma_f32_16x16x32_bf16(ah.v, Bl[nf], acc[mf][nf], 0, 0, 0);
                acc[mf][nf] = __builtin_amdgcn_mfma_f32_16x16x32_bf16(al.v, Bh[nf], acc[mf][nf], 0, 0, 0);
            }
        }
    }

    // ---- epilogue ----------------------------------------------------------
    // C/D layout: col(pixel) = lane&15 (+nf*16), row(channel) = mf*16 + g*4 + r.
    float bb[16];
    #pragma unroll
    for (int mf = 0; mf < 4; ++mf)
        #pragma unroll
        for (int r = 0; r < 4; ++r)
            bb[mf * 4 + r] = b2p[mf * 16 + g * 4 + r];

    // sq = (f2 + b2)^2 in place; pad channels get ~1e36 (-> exp 0)
    #pragma unroll
    for (int mf = 0; mf < 4; ++mf)
        #pragma unroll
        for (int nf = 0; nf < 4; ++nf)
            #pragma unroll
            for (int r = 0; r < 4; ++r) {
                const float f = acc[mf][nf][r] + bb[mf * 4 + r];
                acc[mf][nf][r] = f * f;
            }

    // per-pixel min over 49 channels: lane-local over (mf,r), then xor16/xor32
    float pm[4];
    #pragma unroll
    for (int nf = 0; nf < 4; ++nf) {
        float m = acc[0][nf][0];
        #pragma unroll
        for (int mf = 0; mf < 4; ++mf)
            #pragma unroll
            for (int r = 0; r < 4; ++r)
                m = fminf(m, acc[mf][nf][r]);
        m = fminf(m, __shfl_xor(m, 16));
        m = fminf(m, __shfl_xor(m, 32));
        pm[nf] = m;
    }

    // weighted flow accumulation from padded flow (no bounds checks)
    const float* fpx = flowp + (size_t)h * FP_W + (w0 + pw + col);
    const float* fpy = fpx + (size_t)FP_W * FP_W;
    float sx[4] = {0.f, 0.f, 0.f, 0.f};
    float sy[4] = {0.f, 0.f, 0.f, 0.f};
    float dv[4] = {0.f, 0.f, 0.f, 0.f};

    #pragma unroll
    for (int mf = 0; mf < 4; ++mf) {
        #pragma unroll
        for (int r = 0; r < 4; ++r) {
            const int ch = mf * 16 + g * 4 + r;
            int ki = (ch * 37) >> 8;        // floor(ch/7) for ch<64
            int kj = ch - 7 * ki;
            ki = min(ki, 6);                // pad channels: clamp (d==0 anyway)
            kj = min(kj, 6);
            const int off = ki * FP_W + kj;
            #pragma unroll
            for (int nf = 0; nf < 4; ++nf) {
                const float d = __expf(pm[nf] - acc[mf][nf][r]);
                dv[nf] += d;
                sx[nf] += d * fpx[off + nf * 16];
                sy[nf] += d * fpy[off + nf * 16];
            }
        }
    }

    // cross-lane (4 lanes per pixel: xor 16, 32) and write
    #pragma unroll
    for (int nf = 0; nf < 4; ++nf) {
        float d = dv[nf], x = sx[nf], y = sy[nf];
        d += __shfl_xor(d, 16);  x += __shfl_xor(x, 16);  y += __shfl_xor(y, 16);
        d += __shfl_xor(d, 32);  x += __shfl_xor(x, 32);  y += __shfl_xor(y, 32);
        if (g == 0) {
            const int w = w0 + pw + nf * 16 + col;
            out[(size_t)h * WO + w]                     = x / d;
            out[(size_t)HO * WO + (size_t)h * WO + w]   = y / d;
        }
    }
}

// ---------------------------------------------------------------------------
extern "C" void kernel_launch(void* const* d_in, const int* in_sizes, int n_in,
                              void* d_out, int out_size, void* d_ws, size_t ws_size,
                              hipStream_t stream) {
    const float* reg_feat = (const float*)d_in[0];
    const float* flow     = (const float*)d_in[1];
    const float* wt       = (const float*)d_in[2];
    const float* bt       = (const float*)d_in[3];
    const float* w1       = (const float*)d_in[4];
    const float* b1       = (const float*)d_in[5];
    const float* w2       = (const float*)d_in[6];
    const float* b2       = (const float*)d_in[7];
    float* out = (float*)d_out;
    (void)in_sizes; (void)n_in; (void)out_size; (void)ws_size;

    float* ws    = (float*)d_ws;
    uint4* wpC   = (uint4*)(ws + OFF_WPC);
    float* b2p   = ws + OFF_B2P;
    float* f0    = ws + OFF_F0;
    float* flowp = ws + OFF_F0;          // aliases f0: written after kB, dead before next kA
    float* f1    = ws + OFF_F1;

    repackC<<<26, 256, 0, stream>>>(w2, b2, wpC, b2p);

    for (int b = 0; b < 4; ++b) {
        const float* xb  = reg_feat + (size_t)b * CI * HI * WI;
        const float* flb = flow     + (size_t)b * 2 * HO * WO;
        float*       ob  = out      + (size_t)b * 2 * HO * WO;
        kA<<<512, 256, 0, stream>>>(xb, wt, bt, f0);
        kB<<<512, 256, 0, stream>>>(f0, w1, b1, f1);
        kPad<<<(2 * FP_W * FP_W + 255) / 256, 256, 0, stream>>>(flb, flowp);
        kC<<<1024, 256, 0, stream>>>(f1, wpC, b2p, flowp, ob);
    }
}

// Round 4
// 781.770 us; speedup vs baseline: 2.7495x; 1.2989x over previous
//
#include <hip/hip_runtime.h>

constexpr int HI = 256, WI = 256;   // reg_feat spatial
constexpr int HO = 512, WO = 512;   // upsampled spatial
constexpr int CI = 32;              // feat channels
constexpr int CK = 49;              // 7x7 unfold channels

// ---- ws layout (float offsets) --------------------------------------------
constexpr size_t OFF_WPC = 0;        // w2 frags: 13*2*4*64 uint4 = 26624 f32
constexpr size_t OFF_B2P = 26624;    // padded b2 [64]
constexpr size_t OFF_WPB = 26688;    // w1 frags: 7*2*4*64 uint4 = 14336 f32
constexpr size_t OFF_B1P = 41024;    // padded b1 [64]
constexpr size_t OFF_F0  = 49152;    // f0p u32 [512][512][32] (flowp aliases this)
constexpr size_t OFF_F1  = OFF_F0 + (size_t)HO * WO * CI;   // f1p u32 [49][512][512]

constexpr int FP_W = 518;            // padded flow row (512 + 3 + 3)

using bf16x8 = __attribute__((ext_vector_type(8))) short;
using f32x4  = __attribute__((ext_vector_type(4))) float;

__device__ inline unsigned bf_rne(float x) {           // fp32 -> bf16 bits (RNE)
    unsigned u = __float_as_uint(x);
    return (u + 0x7FFFu + ((u >> 16) & 1u)) >> 16;
}
__device__ inline unsigned pack_split(float v) {       // (hi<<16)|lo split-bf16
    const unsigned hi = bf_rne(v);
    const float vh = __uint_as_float(hi << 16);
    const unsigned lo = bf_rne(v - vh);
    return (hi << 16) | lo;
}

union FragU { uint4 q; bf16x8 v; unsigned u[4]; };

// ---------------------------------------------------------------------------
// Stage A: ConvTranspose2d(32,32,4,s=2,p=1). Output: f0p[h][w][i] packed u32.
// ---------------------------------------------------------------------------
__global__ __launch_bounds__(256, 2)
void kA(const float* __restrict__ x, const float* __restrict__ wt,
        const float* __restrict__ bt, unsigned* __restrict__ f0p)
{
    __shared__ float wl[16 * 1024];  // [tap=kh*4+kw][i][o]
    const int tid = threadIdx.x;
    for (int j = tid; j < 4096; j += 256) {
        const int r = j >> 2, tq = j & 3;       // r = i*32+o
        const float4 v = reinterpret_cast<const float4*>(wt)[j];
        wl[(4 * tq + 0) * 1024 + r] = v.x;
        wl[(4 * tq + 1) * 1024 + r] = v.y;
        wl[(4 * tq + 2) * 1024 + r] = v.z;
        wl[(4 * tq + 3) * 1024 + r] = v.w;
    }
    __syncthreads();

    const int oh  = blockIdx.x;
    const int kh0 = (oh & 1) ? 0 : 1;
    const int ow0 = tid;
    const int kw0 = (ow0 & 1) ? 0 : 1;

    float acc0[32], acc1[32];
    #pragma unroll
    for (int o = 0; o < 32; ++o) { acc0[o] = 0.f; acc1[o] = 0.f; }

    for (int i = 0; i < CI; ++i) {
        const float* xi = x + i * (HI * WI);
        #pragma unroll
        for (int a = 0; a < 2; ++a) {
            const int kh = kh0 + 2 * a;
            const int ih = (oh + 1 - kh) >> 1;
            const bool vh = ((unsigned)ih < (unsigned)HI);
            const float* xr = xi + ih * WI;
            #pragma unroll
            for (int d = 0; d < 2; ++d) {
                const int kw  = kw0 + 2 * d;
                const int iw0 = (ow0 + 1 - kw) >> 1;
                const int iw1 = iw0 + 128;
                const float xv0 = (vh && (unsigned)iw0 < (unsigned)WI) ? xr[iw0] : 0.f;
                const float xv1 = (vh && (unsigned)iw1 < (unsigned)WI) ? xr[iw1] : 0.f;
                const float* wp = wl + (kh * 4 + kw) * 1024 + i * 32;
                #pragma unroll
                for (int o = 0; o < 32; ++o) {
                    const float wv = wp[o];
                    acc0[o] += xv0 * wv;
                    acc1[o] += xv1 * wv;
                }
            }
        }
    }
    // pack split-bf16 and store [h][w][i]
    uint4* dst0 = reinterpret_cast<uint4*>(f0p + ((size_t)oh * WO + ow0) * 32);
    uint4* dst1 = reinterpret_cast<uint4*>(f0p + ((size_t)oh * WO + ow0 + 256) * 32);
    #pragma unroll
    for (int r = 0; r < 8; ++r) {
        uint4 q0, q1;
        q0.x = pack_split(acc0[4 * r + 0] + bt[4 * r + 0]);
        q0.y = pack_split(acc0[4 * r + 1] + bt[4 * r + 1]);
        q0.z = pack_split(acc0[4 * r + 2] + bt[4 * r + 2]);
        q0.w = pack_split(acc0[4 * r + 3] + bt[4 * r + 3]);
        q1.x = pack_split(acc1[4 * r + 0] + bt[4 * r + 0]);
        q1.y = pack_split(acc1[4 * r + 1] + bt[4 * r + 1]);
        q1.z = pack_split(acc1[4 * r + 2] + bt[4 * r + 2]);
        q1.w = pack_split(acc1[4 * r + 3] + bt[4 * r + 3]);
        dst0[r] = q0;
        dst1[r] = q1;
    }
}

// ---------------------------------------------------------------------------
// repack: A-operand fragments for kB (w1, 7 chunks=taps, K=32=i) and
// kC (w2, 13 chunks over (i,t)), split bf16 hi/lo; padded biases.
// Fragment convention (m89-verified, validated in R3):
//   A-frag lane l, elem j: A[row = mf*16 + (l&15)][k = (l>>4)*8 + j]
// ---------------------------------------------------------------------------
__global__ void repack(const float* __restrict__ w1, const float* __restrict__ b1,
                       const float* __restrict__ w2, const float* __restrict__ b2,
                       uint4* __restrict__ wpB, float* __restrict__ b1p,
                       uint4* __restrict__ wpC, float* __restrict__ b2p)
{
    const int j = blockIdx.x * 256 + threadIdx.x;
    if (j < 64) {
        b2p[j] = (j < CK) ? b2[j] : 1e18f;
        b1p[j] = (j < CK) ? b1[j] : 0.f;
    }
    if (j < 7 * 2 * 4 * 64) {               // kB: chunk t, k = i
        const int t    = j >> 9;
        const int s    = (j >> 8) & 1;
        const int mf   = (j >> 6) & 3;
        const int lane = j & 63;
        const int o = mf * 16 + (lane & 15);
        unsigned b[8];
        #pragma unroll
        for (int jj = 0; jj < 8; ++jj) {
            const int i = (lane >> 4) * 8 + jj;
            float v = (o < CK) ? w1[o * 224 + i * 7 + t] : 0.f;
            const unsigned hi = bf_rne(v);
            b[jj] = (s == 0) ? hi : bf_rne(v - __uint_as_float(hi << 16));
        }
        uint4 q;
        q.x = (b[1] << 16) | b[0];
        q.y = (b[3] << 16) | b[2];
        q.z = (b[5] << 16) | b[4];
        q.w = (b[7] << 16) | b[6];
        wpB[((t * 2 + s) * 4 + mf) * 64 + lane] = q;
    }
    if (j < 13 * 2 * 4 * 64) {              // kC: chunk c, k-group g -> i=4c+g, t=j
        const int c    = j >> 9;
        const int s    = (j >> 8) & 1;
        const int mf   = (j >> 6) & 3;
        const int lane = j & 63;
        const int o = mf * 16 + (lane & 15);
        const int i = 4 * c + (lane >> 4);
        unsigned b[8];
        #pragma unroll
        for (int t = 0; t < 8; ++t) {
            float v = 0.f;
            if (t < 7 && o < CK && i < CK) v = w2[o * 343 + i * 7 + t];
            const unsigned hi = bf_rne(v);
            b[t] = (s == 0) ? hi : bf_rne(v - __uint_as_float(hi << 16));
        }
        uint4 q;
        q.x = (b[1] << 16) | b[0];
        q.y = (b[3] << 16) | b[2];
        q.z = (b[5] << 16) | b[4];
        q.w = (b[7] << 16) | b[6];
        wpC[((c * 2 + s) * 4 + mf) * 64 + lane] = q;
    }
}

// ---------------------------------------------------------------------------
// kPad: flowp[p][hh][ww] = flow[p][hh-3][ww-3], zero outside. [2][518][518]
// ---------------------------------------------------------------------------
__global__ void kPad(const float* __restrict__ flow, float* __restrict__ flowp)
{
    const int idx = blockIdx.x * 256 + threadIdx.x;
    if (idx >= 2 * FP_W * FP_W) return;
    const int p  = idx / (FP_W * FP_W);
    const int q  = idx - p * (FP_W * FP_W);
    const int hh = q / FP_W;
    const int ww = q - hh * FP_W;
    float v = 0.f;
    const int hs = hh - 3, ws = ww - 3;
    if ((unsigned)hs < (unsigned)HO && (unsigned)ws < (unsigned)WO)
        v = flow[p * (HO * WO) + hs * WO + ws];
    flowp[idx] = v;
}

// ---------------------------------------------------------------------------
// kB: 7x1 vertical conv 32->49 via split-bf16 MFMA. No LDS.
// Wave tile = 64 px (one row) x 64 ch. Chunk = tap t; k = input channel i.
// B-frags: 2x dwordx4 from f0p[h+t-3][w][i] (k contiguous). Output: f1p u32.
// ---------------------------------------------------------------------------
__global__ __launch_bounds__(256, 2)
void kB(const unsigned* __restrict__ f0p, const uint4* __restrict__ wpB,
        const float* __restrict__ b1p, unsigned* __restrict__ f1p)
{
    const int tid  = threadIdx.x;
    const int h    = blockIdx.x >> 1;
    const int lane = tid & 63;
    const int n    = lane & 15;
    const int g    = lane >> 4;
    const int w0   = ((blockIdx.x & 1) << 8) + ((tid >> 6) << 6);  // wave col base

    f32x4 acc[4][4];
    #pragma unroll
    for (int mf = 0; mf < 4; ++mf)
        #pragma unroll
        for (int nf = 0; nf < 4; ++nf)
            acc[mf][nf] = (f32x4){0.f, 0.f, 0.f, 0.f};

    #pragma unroll
    for (int t = 0; t < 7; ++t) {
        const int hr = h + t - 3;
        if ((unsigned)hr < (unsigned)HO) {
            bf16x8 Bh[4], Bl[4];
            #pragma unroll
            for (int nf = 0; nf < 4; ++nf) {
                const size_t base = ((size_t)hr * WO + (w0 + nf * 16 + n)) * 32 + g * 8;
                const uint4 q0 = *reinterpret_cast<const uint4*>(f0p + base);
                const uint4 q1 = *reinterpret_cast<const uint4*>(f0p + base + 4);
                const unsigned u[8] = {q0.x, q0.y, q0.z, q0.w, q1.x, q1.y, q1.z, q1.w};
                FragU fh, fl;
                #pragma unroll
                for (int r = 0; r < 4; ++r) {
                    fh.u[r] = (u[2 * r + 1] & 0xFFFF0000u) | (u[2 * r] >> 16);
                    fl.u[r] = (u[2 * r + 1] << 16) | (u[2 * r] & 0xFFFFu);
                }
                Bh[nf] = fh.v;
                Bl[nf] = fl.v;
            }
            #pragma unroll
            for (int mf = 0; mf < 4; ++mf) {
                FragU ah, al;
                ah.q = wpB[((t * 2 + 0) * 4 + mf) * 64 + lane];
                al.q = wpB[((t * 2 + 1) * 4 + mf) * 64 + lane];
                #pragma unroll
                for (int nf = 0; nf < 4; ++nf) {
                    acc[mf][nf] = __builtin_amdgcn_mfma_f32_16x16x32_bf16(ah.v, Bh[nf], acc[mf][nf], 0, 0, 0);
                    acc[mf][nf] = __builtin_amdgcn_mfma_f32_16x16x32_bf16(ah.v, Bl[nf], acc[mf][nf], 0, 0, 0);
                    acc[mf][nf] = __builtin_amdgcn_mfma_f32_16x16x32_bf16(al.v, Bh[nf], acc[mf][nf], 0, 0, 0);
                }
            }
        }
    }

    // epilogue: C/D col(pixel) = lane&15 (+nf*16), row(channel) = mf*16+g*4+r
    #pragma unroll
    for (int mf = 0; mf < 4; ++mf)
        #pragma unroll
        for (int r = 0; r < 4; ++r) {
            const int o = mf * 16 + g * 4 + r;
            if (o < CK) {
                const float bv = b1p[o];
                #pragma unroll
                for (int nf = 0; nf < 4; ++nf) {
                    const int w = w0 + nf * 16 + n;
                    f1p[((size_t)o * HO + h) * WO + w] = pack_split(acc[mf][nf][r] + bv);
                }
            }
        }
}

// ---------------------------------------------------------------------------
// kC: 1x7 conv 49->49 via split-bf16 MFMA + softmax + flow average.
// f1p is already packed u32 -> LDS staging is a straight copy.
// ---------------------------------------------------------------------------
__global__ __launch_bounds__(256, 3)
void kC(const unsigned* __restrict__ f1p, const uint4* __restrict__ wpC,
        const float* __restrict__ b2p, const float* __restrict__ flowp,
        float* __restrict__ out)
{
    constexpr int LC = 264;                 // staged row length (256 + 3 + 3 + pad2)
    __shared__ unsigned L[CK * LC];         // packed (hi<<16|lo) pairs

    const int tid = threadIdx.x;
    const int h   = blockIdx.x >> 1;
    const int w0  = (blockIdx.x & 1) << 8;

    for (int idx = tid; idx < CK * LC; idx += 256) {
        const int i = idx / LC;
        const int q = idx - i * LC;
        const int ww = w0 - 3 + q;
        L[idx] = ((unsigned)ww < (unsigned)WO) ? f1p[((size_t)i * HO + h) * WO + ww] : 0u;
    }
    __syncthreads();

    const int wv   = tid >> 6;
    const int lane = tid & 63;
    const int col  = lane & 15;
    const int g    = lane >> 4;
    const int pw   = wv * 64;

    const int vb   = g * LC + pw + col;     // chunks 0..11: i = 4c+g
    const int vb12 = 48 * LC + pw + col;    // chunk 12: only g==0 (i=48) live

    f32x4 acc[4][4];
    #pragma unroll
    for (int mf = 0; mf < 4; ++mf)
        #pragma unroll
        for (int nf = 0; nf < 4; ++nf)
            acc[mf][nf] = (f32x4){0.f, 0.f, 0.f, 0.f};

    #pragma unroll
    for (int c = 0; c < 13; ++c) {
        bf16x8 Bh[4], Bl[4];
        #pragma unroll
        for (int nf = 0; nf < 4; ++nf) {
            unsigned u[8];
            #pragma unroll
            for (int j = 0; j < 7; ++j) {
                const int off = (c < 12) ? (vb + c * (4 * LC) + nf * 16 + j)
                                         : (vb12 + nf * 16 + j);
                u[j] = L[off];
            }
            u[7] = 0u;
            FragU fh, fl;
            #pragma unroll
            for (int r = 0; r < 4; ++r) {
                fh.u[r] = (u[2 * r + 1] & 0xFFFF0000u) | (u[2 * r] >> 16);
                fl.u[r] = (u[2 * r + 1] << 16) | (u[2 * r] & 0xFFFFu);
            }
            Bh[nf] = fh.v;
            Bl[nf] = fl.v;
        }
        #pragma unroll
        for (int mf = 0; mf < 4; ++mf) {
            FragU ah, al;
            ah.q = wpC[((c * 2 + 0) * 4 + mf) * 64 + lane];
            al.q = wpC[((c * 2 + 1) * 4 + mf) * 64 + lane];
            #pragma unroll
            for (int nf = 0; nf < 4; ++nf) {
                acc[mf][nf] = __builtin_amdgcn_mfma_f32_16x16x32_bf16(ah.v, Bh[nf], acc[mf][nf], 0, 0, 0);
                acc[mf][nf] = __builtin_amdgcn_mfma_f32_16x16x32_bf16(ah.v, Bl[nf], acc[mf][nf], 0, 0, 0);
                acc[mf][nf] = __builtin_amdgcn_mfma_f32_16x16x32_bf16(al.v, Bh[nf], acc[mf][nf], 0, 0, 0);
            }
        }
    }

    // ---- epilogue ----------------------------------------------------------
    float bb[16];
    #pragma unroll
    for (int mf = 0; mf < 4; ++mf)
        #pragma unroll
        for (int r = 0; r < 4; ++r)
            bb[mf * 4 + r] = b2p[mf * 16 + g * 4 + r];

    #pragma unroll
    for (int mf = 0; mf < 4; ++mf)
        #pragma unroll
        for (int nf = 0; nf < 4; ++nf)
            #pragma unroll
            for (int r = 0; r < 4; ++r) {
                const float f = acc[mf][nf][r] + bb[mf * 4 + r];
                acc[mf][nf][r] = f * f;
            }

    float pm[4];
    #pragma unroll
    for (int nf = 0; nf < 4; ++nf) {
        float m = acc[0][nf][0];
        #pragma unroll
        for (int mf = 0; mf < 4; ++mf)
            #pragma unroll
            for (int r = 0; r < 4; ++r)
                m = fminf(m, acc[mf][nf][r]);
        m = fminf(m, __shfl_xor(m, 16));
        m = fminf(m, __shfl_xor(m, 32));
        pm[nf] = m;
    }

    const float* fpx = flowp + (size_t)h * FP_W + (w0 + pw + col);
    const float* fpy = fpx + (size_t)FP_W * FP_W;
    float sx[4] = {0.f, 0.f, 0.f, 0.f};
    float sy[4] = {0.f, 0.f, 0.f, 0.f};
    float dv[4] = {0.f, 0.f, 0.f, 0.f};

    #pragma unroll
    for (int mf = 0; mf < 4; ++mf) {
        #pragma unroll
        for (int r = 0; r < 4; ++r) {
            const int ch = mf * 16 + g * 4 + r;
            int ki = (ch * 37) >> 8;        // floor(ch/7) for ch<64
            int kj = ch - 7 * ki;
            ki = min(ki, 6);
            kj = min(kj, 6);
            const int off = ki * FP_W + kj;
            #pragma unroll
            for (int nf = 0; nf < 4; ++nf) {
                const float d = __expf(pm[nf] - acc[mf][nf][r]);
                dv[nf] += d;
                sx[nf] += d * fpx[off + nf * 16];
                sy[nf] += d * fpy[off + nf * 16];
            }
        }
    }

    #pragma unroll
    for (int nf = 0; nf < 4; ++nf) {
        float d = dv[nf], x = sx[nf], y = sy[nf];
        d += __shfl_xor(d, 16);  x += __shfl_xor(x, 16);  y += __shfl_xor(y, 16);
        d += __shfl_xor(d, 32);  x += __shfl_xor(x, 32);  y += __shfl_xor(y, 32);
        if (g == 0) {
            const int w = w0 + pw + nf * 16 + col;
            out[(size_t)h * WO + w]                     = x / d;
            out[(size_t)HO * WO + (size_t)h * WO + w]   = y / d;
        }
    }
}

// ---------------------------------------------------------------------------
extern "C" void kernel_launch(void* const* d_in, const int* in_sizes, int n_in,
                              void* d_out, int out_size, void* d_ws, size_t ws_size,
                              hipStream_t stream) {
    const float* reg_feat = (const float*)d_in[0];
    const float* flow     = (const float*)d_in[1];
    const float* wt       = (const float*)d_in[2];
    const float* bt       = (const float*)d_in[3];
    const float* w1       = (const float*)d_in[4];
    const float* b1       = (const float*)d_in[5];
    const float* w2       = (const float*)d_in[6];
    const float* b2       = (const float*)d_in[7];
    float* out = (float*)d_out;
    (void)in_sizes; (void)n_in; (void)out_size; (void)ws_size;

    float*    ws    = (float*)d_ws;
    uint4*    wpC   = (uint4*)(ws + OFF_WPC);
    float*    b2p   = ws + OFF_B2P;
    uint4*    wpB   = (uint4*)(ws + OFF_WPB);
    float*    b1p   = ws + OFF_B1P;
    unsigned* f0p   = (unsigned*)(ws + OFF_F0);
    float*    flowp = ws + OFF_F0;          // aliases f0p: dead by the time kPad runs
    unsigned* f1p   = (unsigned*)(ws + OFF_F1);

    repack<<<26, 256, 0, stream>>>(w1, b1, w2, b2, wpB, b1p, wpC, b2p);

    for (int b = 0; b < 4; ++b) {
        const float* xb  = reg_feat + (size_t)b * CI * HI * WI;
        const float* flb = flow     + (size_t)b * 2 * HO * WO;
        float*       ob  = out      + (size_t)b * 2 * HO * WO;
        kA<<<512, 256, 0, stream>>>(xb, wt, bt, f0p);
        kB<<<1024, 256, 0, stream>>>(f0p, wpB, b1p, f1p);
        kPad<<<(2 * FP_W * FP_W + 255) / 256, 256, 0, stream>>>(flb, flowp);
        kC<<<1024, 256, 0, stream>>>(f1p, wpC, b2p, flowp, ob);
    }
}

// Round 5
// 635.626 us; speedup vs baseline: 3.3817x; 1.2299x over previous
//
#include <hip/hip_runtime.h>

constexpr int HI = 256, WI = 256;   // reg_feat spatial
constexpr int HO = 512, WO = 512;   // upsampled spatial
constexpr int CI = 32;              // feat channels
constexpr int CK = 49;              // 7x7 unfold channels

// ---- ws layout (float offsets) --------------------------------------------
constexpr size_t OFF_WPC = 0;        // w2 frags: 13*2*4*64 uint4 = 26624 f32
constexpr size_t OFF_B2P = 26624;    // padded b2 [64]
constexpr size_t OFF_WPB = 26688;    // w1 frags: 7*2*4*64 uint4 = 14336 f32
constexpr size_t OFF_B1P = 41024;    // padded b1 [64]
constexpr size_t OFF_F0  = 49152;    // f0p u32 [512][512][32] (flowp aliases this)
constexpr size_t OFF_F1  = OFF_F0 + (size_t)HO * WO * CI;   // f1p u32 [49][512][512]

constexpr int FP_W = 518;            // padded flow row (512 + 3 + 3)

using bf16x8 = __attribute__((ext_vector_type(8))) short;
using f32x4  = __attribute__((ext_vector_type(4))) float;

__device__ inline unsigned bf_rne(float x) {           // fp32 -> bf16 bits (RNE)
    unsigned u = __float_as_uint(x);
    return (u + 0x7FFFu + ((u >> 16) & 1u)) >> 16;
}
__device__ inline unsigned pack_split(float v) {       // (hi<<16)|lo split-bf16
    const unsigned hi = bf_rne(v);
    const float vh = __uint_as_float(hi << 16);
    const unsigned lo = bf_rne(v - vh);
    return (hi << 16) | lo;
}

union FragU { uint4 q; bf16x8 v; unsigned u[4]; };

// v_perm selectors: from packed pair (v1,v0) build (hi16(v1)<<16)|hi16(v0) etc.
constexpr unsigned PERM_HI = 0x07060302u;
constexpr unsigned PERM_LO = 0x05040100u;

// ---------------------------------------------------------------------------
// Stage A: ConvTranspose2d(32,32,4,s=2,p=1). Output: f0p[h][w][i] packed u32.
// ---------------------------------------------------------------------------
__global__ __launch_bounds__(256, 2)
void kA(const float* __restrict__ x, const float* __restrict__ wt,
        const float* __restrict__ bt, unsigned* __restrict__ f0p)
{
    __shared__ float wl[16 * 1024];  // [tap=kh*4+kw][i][o]
    const int tid = threadIdx.x;
    for (int j = tid; j < 4096; j += 256) {
        const int r = j >> 2, tq = j & 3;       // r = i*32+o
        const float4 v = reinterpret_cast<const float4*>(wt)[j];
        wl[(4 * tq + 0) * 1024 + r] = v.x;
        wl[(4 * tq + 1) * 1024 + r] = v.y;
        wl[(4 * tq + 2) * 1024 + r] = v.z;
        wl[(4 * tq + 3) * 1024 + r] = v.w;
    }
    __syncthreads();

    const int oh  = blockIdx.x;
    const int kh0 = (oh & 1) ? 0 : 1;
    const int ow0 = tid;
    const int kw0 = (ow0 & 1) ? 0 : 1;

    float acc0[32], acc1[32];
    #pragma unroll
    for (int o = 0; o < 32; ++o) { acc0[o] = 0.f; acc1[o] = 0.f; }

    for (int i = 0; i < CI; ++i) {
        const float* xi = x + i * (HI * WI);
        #pragma unroll
        for (int a = 0; a < 2; ++a) {
            const int kh = kh0 + 2 * a;
            const int ih = (oh + 1 - kh) >> 1;
            const bool vh = ((unsigned)ih < (unsigned)HI);
            const float* xr = xi + ih * WI;
            #pragma unroll
            for (int d = 0; d < 2; ++d) {
                const int kw  = kw0 + 2 * d;
                const int iw0 = (ow0 + 1 - kw) >> 1;
                const int iw1 = iw0 + 128;
                const float xv0 = (vh && (unsigned)iw0 < (unsigned)WI) ? xr[iw0] : 0.f;
                const float xv1 = (vh && (unsigned)iw1 < (unsigned)WI) ? xr[iw1] : 0.f;
                const float* wp = wl + (kh * 4 + kw) * 1024 + i * 32;
                #pragma unroll
                for (int o = 0; o < 32; ++o) {
                    const float wv = wp[o];
                    acc0[o] += xv0 * wv;
                    acc1[o] += xv1 * wv;
                }
            }
        }
    }
    uint4* dst0 = reinterpret_cast<uint4*>(f0p + ((size_t)oh * WO + ow0) * 32);
    uint4* dst1 = reinterpret_cast<uint4*>(f0p + ((size_t)oh * WO + ow0 + 256) * 32);
    #pragma unroll
    for (int r = 0; r < 8; ++r) {
        uint4 q0, q1;
        q0.x = pack_split(acc0[4 * r + 0] + bt[4 * r + 0]);
        q0.y = pack_split(acc0[4 * r + 1] + bt[4 * r + 1]);
        q0.z = pack_split(acc0[4 * r + 2] + bt[4 * r + 2]);
        q0.w = pack_split(acc0[4 * r + 3] + bt[4 * r + 3]);
        q1.x = pack_split(acc1[4 * r + 0] + bt[4 * r + 0]);
        q1.y = pack_split(acc1[4 * r + 1] + bt[4 * r + 1]);
        q1.z = pack_split(acc1[4 * r + 2] + bt[4 * r + 2]);
        q1.w = pack_split(acc1[4 * r + 3] + bt[4 * r + 3]);
        dst0[r] = q0;
        dst1[r] = q1;
    }
}

// ---------------------------------------------------------------------------
// repack: A-fragments for kB (chunk=t, k=i) and kC (chunk c: kg=4c+g,
// oct=kg/7, t=kg%7, i=oct*8+j), split bf16 hi/lo; padded biases.
// A-frag convention (verified R3/R4): lane l elem j -> A[mf*16+(l&15)][(l>>4)*8+j]
// ---------------------------------------------------------------------------
__global__ void repack(const float* __restrict__ w1, const float* __restrict__ b1,
                       const float* __restrict__ w2, const float* __restrict__ b2,
                       uint4* __restrict__ wpB, float* __restrict__ b1p,
                       uint4* __restrict__ wpC, float* __restrict__ b2p)
{
    const int j = blockIdx.x * 256 + threadIdx.x;
    if (j < 64) {
        b2p[j] = (j < CK) ? b2[j] : 1e18f;
        b1p[j] = (j < CK) ? b1[j] : 0.f;
    }
    if (j < 7 * 2 * 4 * 64) {               // kB: chunk t, k = i
        const int t    = j >> 9;
        const int s    = (j >> 8) & 1;
        const int mf   = (j >> 6) & 3;
        const int lane = j & 63;
        const int o = mf * 16 + (lane & 15);
        unsigned b[8];
        #pragma unroll
        for (int jj = 0; jj < 8; ++jj) {
            const int i = (lane >> 4) * 8 + jj;
            float v = (o < CK) ? w1[o * 224 + i * 7 + t] : 0.f;
            const unsigned hi = bf_rne(v);
            b[jj] = (s == 0) ? hi : bf_rne(v - __uint_as_float(hi << 16));
        }
        uint4 q;
        q.x = (b[1] << 16) | b[0];
        q.y = (b[3] << 16) | b[2];
        q.z = (b[5] << 16) | b[4];
        q.w = (b[7] << 16) | b[6];
        wpB[((t * 2 + s) * 4 + mf) * 64 + lane] = q;
    }
    if (j < 13 * 2 * 4 * 64) {              // kC: kg=4c+g -> (oct,t); i=oct*8+jj
        const int c    = j >> 9;
        const int s    = (j >> 8) & 1;
        const int mf   = (j >> 6) & 3;
        const int lane = j & 63;
        const int o   = mf * 16 + (lane & 15);
        const int kg  = 4 * c + (lane >> 4);
        const int oct = kg / 7;
        const int t   = kg - 7 * oct;
        unsigned b[8];
        #pragma unroll
        for (int jj = 0; jj < 8; ++jj) {
            const int i = oct * 8 + jj;
            float v = 0.f;
            if (kg < CK && o < CK && i < CK) v = w2[o * 343 + i * 7 + t];
            const unsigned hi = bf_rne(v);
            b[jj] = (s == 0) ? hi : bf_rne(v - __uint_as_float(hi << 16));
        }
        uint4 q;
        q.x = (b[1] << 16) | b[0];
        q.y = (b[3] << 16) | b[2];
        q.z = (b[5] << 16) | b[4];
        q.w = (b[7] << 16) | b[6];
        wpC[((c * 2 + s) * 4 + mf) * 64 + lane] = q;
    }
}

// ---------------------------------------------------------------------------
// kPad: flowp[p][hh][ww] = flow[p][hh-3][ww-3], zero outside. [2][518][518]
// ---------------------------------------------------------------------------
__global__ void kPad(const float* __restrict__ flow, float* __restrict__ flowp)
{
    const int idx = blockIdx.x * 256 + threadIdx.x;
    if (idx >= 2 * FP_W * FP_W) return;
    const int p  = idx / (FP_W * FP_W);
    const int q  = idx - p * (FP_W * FP_W);
    const int hh = q / FP_W;
    const int ww = q - hh * FP_W;
    float v = 0.f;
    const int hs = hh - 3, ws = ww - 3;
    if ((unsigned)hs < (unsigned)HO && (unsigned)ws < (unsigned)WO)
        v = flow[p * (HO * WO) + hs * WO + ws];
    flowp[idx] = v;
}

// ---------------------------------------------------------------------------
// kB: 7x1 vertical conv 32->49 via split-bf16 MFMA. No LDS.
// B-frags: 2x dwordx4 from f0p[h+t-3][w][i], v_perm hi/lo split.
// ---------------------------------------------------------------------------
__global__ __launch_bounds__(256, 2)
void kB(const unsigned* __restrict__ f0p, const uint4* __restrict__ wpB,
        const float* __restrict__ b1p, unsigned* __restrict__ f1p)
{
    const int tid  = threadIdx.x;
    const int h    = blockIdx.x >> 1;
    const int lane = tid & 63;
    const int n    = lane & 15;
    const int g    = lane >> 4;
    const int w0   = ((blockIdx.x & 1) << 8) + ((tid >> 6) << 6);  // wave col base

    f32x4 acc[4][4];
    #pragma unroll
    for (int mf = 0; mf < 4; ++mf)
        #pragma unroll
        for (int nf = 0; nf < 4; ++nf)
            acc[mf][nf] = (f32x4){0.f, 0.f, 0.f, 0.f};

    #pragma unroll
    for (int t = 0; t < 7; ++t) {
        const int hr = h + t - 3;
        if ((unsigned)hr < (unsigned)HO) {
            bf16x8 Bh[4], Bl[4];
            #pragma unroll
            for (int nf = 0; nf < 4; ++nf) {
                const size_t base = ((size_t)hr * WO + (w0 + nf * 16 + n)) * 32 + g * 8;
                const uint4 q0 = *reinterpret_cast<const uint4*>(f0p + base);
                const uint4 q1 = *reinterpret_cast<const uint4*>(f0p + base + 4);
                const unsigned u[8] = {q0.x, q0.y, q0.z, q0.w, q1.x, q1.y, q1.z, q1.w};
                FragU fh, fl;
                #pragma unroll
                for (int r = 0; r < 4; ++r) {
                    fh.u[r] = __builtin_amdgcn_perm(u[2 * r + 1], u[2 * r], PERM_HI);
                    fl.u[r] = __builtin_amdgcn_perm(u[2 * r + 1], u[2 * r], PERM_LO);
                }
                Bh[nf] = fh.v;
                Bl[nf] = fl.v;
            }
            #pragma unroll
            for (int mf = 0; mf < 4; ++mf) {
                FragU ah, al;
                ah.q = wpB[((t * 2 + 0) * 4 + mf) * 64 + lane];
                al.q = wpB[((t * 2 + 1) * 4 + mf) * 64 + lane];
                #pragma unroll
                for (int nf = 0; nf < 4; ++nf) {
                    acc[mf][nf] = __builtin_amdgcn_mfma_f32_16x16x32_bf16(ah.v, Bh[nf], acc[mf][nf], 0, 0, 0);
                    acc[mf][nf] = __builtin_amdgcn_mfma_f32_16x16x32_bf16(ah.v, Bl[nf], acc[mf][nf], 0, 0, 0);
                    acc[mf][nf] = __builtin_amdgcn_mfma_f32_16x16x32_bf16(al.v, Bh[nf], acc[mf][nf], 0, 0, 0);
                }
            }
        }
    }

    #pragma unroll
    for (int mf = 0; mf < 4; ++mf)
        #pragma unroll
        for (int r = 0; r < 4; ++r) {
            const int o = mf * 16 + g * 4 + r;
            if (o < CK) {
                const float bv = b1p[o];
                #pragma unroll
                for (int nf = 0; nf < 4; ++nf) {
                    const int w = w0 + nf * 16 + n;
                    f1p[((size_t)o * HO + h) * WO + w] = pack_split(acc[mf][nf][r] + bv);
                }
            }
        }
}

// ---------------------------------------------------------------------------
// kC: 1x7 conv 49->49 via split-bf16 MFMA + softmax + flow average.
// 128-px strips (grid 2048). LDS: transposed hi/lo planes [q=134][ipad=56]
// stored as uint4[q*7+oct] so every B-fragment is ONE aligned ds_read_b128.
// k-enum: kg=4c+g -> oct=kg/7, t=kg%7; elem j -> i=oct*8+j; B = x[i][pix+t].
// ---------------------------------------------------------------------------
__global__ __launch_bounds__(256, 4)
void kC(const unsigned* __restrict__ f1p, const uint4* __restrict__ wpC,
        const float* __restrict__ b2p, const float* __restrict__ flowp,
        float* __restrict__ out)
{
    __shared__ uint4 Lh4[134 * 7];          // hi-plane, rows of 7 uint4 (56 bf16)
    __shared__ uint4 Ll4[134 * 7];          // lo-plane
    unsigned* Lh = reinterpret_cast<unsigned*>(Lh4);
    unsigned* Ll = reinterpret_cast<unsigned*>(Ll4);

    const int tid = threadIdx.x;
    const int h   = blockIdx.x >> 2;
    const int w0  = (blockIdx.x & 3) << 7;

    // stage i-pairs 0..23 (i=0..47): one u32 word = 2 adjacent i per plane
    for (int idx = tid; idx < 24 * 134; idx += 256) {
        const int ip = idx / 134;
        const int q  = idx - ip * 134;
        const int ww = w0 - 3 + q;
        unsigned v0 = 0u, v1 = 0u;
        if ((unsigned)ww < (unsigned)WO) {
            v0 = f1p[((size_t)(2 * ip) * HO + h) * WO + ww];
            v1 = f1p[((size_t)(2 * ip + 1) * HO + h) * WO + ww];
        }
        Lh[q * 28 + ip] = __builtin_amdgcn_perm(v1, v0, PERM_HI);
        Ll[q * 28 + ip] = __builtin_amdgcn_perm(v1, v0, PERM_LO);
    }
    // tail: i=48 real, i=49..55 zero (avoid NaN garbage under A=0)
    for (int idx = tid; idx < 134 * 4; idx += 256) {
        const int q  = idx >> 2;
        const int p4 = idx & 3;
        unsigned hw = 0u, lw = 0u;
        if (p4 == 0) {
            const int ww = w0 - 3 + q;
            unsigned v0 = 0u;
            if ((unsigned)ww < (unsigned)WO)
                v0 = f1p[((size_t)48 * HO + h) * WO + ww];
            hw = v0 >> 16;
            lw = v0 & 0xFFFFu;
        }
        Lh[q * 28 + 24 + p4] = hw;
        Ll[q * 28 + 24 + p4] = lw;
    }
    __syncthreads();

    const int wv   = tid >> 6;
    const int lane = tid & 63;
    const int col  = lane & 15;
    const int g    = lane >> 4;
    const int pw   = wv << 5;               // 32 px per wave
    const int pix  = pw + col;

    f32x4 acc[4][2];
    #pragma unroll
    for (int mf = 0; mf < 4; ++mf) {
        acc[mf][0] = (f32x4){0.f, 0.f, 0.f, 0.f};
        acc[mf][1] = (f32x4){0.f, 0.f, 0.f, 0.f};
    }

    #pragma unroll
    for (int c = 0; c < 13; ++c) {
        const int kg  = 4 * c + g;
        const int oct = (kg * 37) >> 8;     // kg/7 for kg<=51
        const int t   = kg - 7 * oct;
        const int bq  = (pix + t) * 7 + oct;
        FragU bh0, bl0, bh1, bl1;
        bh0.q = Lh4[bq];        bl0.q = Ll4[bq];
        bh1.q = Lh4[bq + 112];  bl1.q = Ll4[bq + 112];   // nf=1: +16px*7
        #pragma unroll
        for (int mf = 0; mf < 4; ++mf) {
            FragU ah, al;
            ah.q = wpC[((c * 2 + 0) * 4 + mf) * 64 + lane];
            al.q = wpC[((c * 2 + 1) * 4 + mf) * 64 + lane];
            acc[mf][0] = __builtin_amdgcn_mfma_f32_16x16x32_bf16(ah.v, bh0.v, acc[mf][0], 0, 0, 0);
            acc[mf][0] = __builtin_amdgcn_mfma_f32_16x16x32_bf16(ah.v, bl0.v, acc[mf][0], 0, 0, 0);
            acc[mf][0] = __builtin_amdgcn_mfma_f32_16x16x32_bf16(al.v, bh0.v, acc[mf][0], 0, 0, 0);
            acc[mf][1] = __builtin_amdgcn_mfma_f32_16x16x32_bf16(ah.v, bh1.v, acc[mf][1], 0, 0, 0);
            acc[mf][1] = __builtin_amdgcn_mfma_f32_16x16x32_bf16(ah.v, bl1.v, acc[mf][1], 0, 0, 0);
            acc[mf][1] = __builtin_amdgcn_mfma_f32_16x16x32_bf16(al.v, bh1.v, acc[mf][1], 0, 0, 0);
        }
    }

    // ---- epilogue: C/D col(pixel)=lane&15 (+nf*16), row(ch)=mf*16+g*4+r ----
    float bb[16];
    #pragma unroll
    for (int mf = 0; mf < 4; ++mf)
        #pragma unroll
        for (int r = 0; r < 4; ++r)
            bb[mf * 4 + r] = b2p[mf * 16 + g * 4 + r];

    #pragma unroll
    for (int mf = 0; mf < 4; ++mf)
        #pragma unroll
        for (int nf = 0; nf < 2; ++nf)
            #pragma unroll
            for (int r = 0; r < 4; ++r) {
                const float f = acc[mf][nf][r] + bb[mf * 4 + r];
                acc[mf][nf][r] = f * f;
            }

    float pm[2];
    #pragma unroll
    for (int nf = 0; nf < 2; ++nf) {
        float m = acc[0][nf][0];
        #pragma unroll
        for (int mf = 0; mf < 4; ++mf)
            #pragma unroll
            for (int r = 0; r < 4; ++r)
                m = fminf(m, acc[mf][nf][r]);
        m = fminf(m, __shfl_xor(m, 16));
        m = fminf(m, __shfl_xor(m, 32));
        pm[nf] = m;
    }

    const float* fpx = flowp + (size_t)h * FP_W + (w0 + pw + col);
    const float* fpy = fpx + (size_t)FP_W * FP_W;
    float sx[2] = {0.f, 0.f};
    float sy[2] = {0.f, 0.f};
    float dv[2] = {0.f, 0.f};

    #pragma unroll
    for (int mf = 0; mf < 4; ++mf) {
        #pragma unroll
        for (int r = 0; r < 4; ++r) {
            const int ch = mf * 16 + g * 4 + r;
            int ki = (ch * 37) >> 8;        // floor(ch/7) for ch<64
            int kj = ch - 7 * ki;
            ki = min(ki, 6);
            kj = min(kj, 6);
            const int off = ki * FP_W + kj;
            #pragma unroll
            for (int nf = 0; nf < 2; ++nf) {
                const float d = __expf(pm[nf] - acc[mf][nf][r]);
                dv[nf] += d;
                sx[nf] += d * fpx[off + nf * 16];
                sy[nf] += d * fpy[off + nf * 16];
            }
        }
    }

    #pragma unroll
    for (int nf = 0; nf < 2; ++nf) {
        float d = dv[nf], x = sx[nf], y = sy[nf];
        d += __shfl_xor(d, 16);  x += __shfl_xor(x, 16);  y += __shfl_xor(y, 16);
        d += __shfl_xor(d, 32);  x += __shfl_xor(x, 32);  y += __shfl_xor(y, 32);
        if (g == 0) {
            const int w = w0 + pw + nf * 16 + col;
            out[(size_t)h * WO + w]                     = x / d;
            out[(size_t)HO * WO + (size_t)h * WO + w]   = y / d;
        }
    }
}

// ---------------------------------------------------------------------------
extern "C" void kernel_launch(void* const* d_in, const int* in_sizes, int n_in,
                              void* d_out, int out_size, void* d_ws, size_t ws_size,
                              hipStream_t stream) {
    const float* reg_feat = (const float*)d_in[0];
    const float* flow     = (const float*)d_in[1];
    const float* wt       = (const float*)d_in[2];
    const float* bt       = (const float*)d_in[3];
    const float* w1       = (const float*)d_in[4];
    const float* b1       = (const float*)d_in[5];
    const float* w2       = (const float*)d_in[6];
    const float* b2       = (const float*)d_in[7];
    float* out = (float*)d_out;
    (void)in_sizes; (void)n_in; (void)out_size; (void)ws_size;

    float*    ws    = (float*)d_ws;
    uint4*    wpC   = (uint4*)(ws + OFF_WPC);
    float*    b2p   = ws + OFF_B2P;
    uint4*    wpB   = (uint4*)(ws + OFF_WPB);
    float*    b1p   = ws + OFF_B1P;
    unsigned* f0p   = (unsigned*)(ws + OFF_F0);
    float*    flowp = ws + OFF_F0;          // aliases f0p: dead by the time kPad runs
    unsigned* f1p   = (unsigned*)(ws + OFF_F1);

    repack<<<26, 256, 0, stream>>>(w1, b1, w2, b2, wpB, b1p, wpC, b2p);

    for (int b = 0; b < 4; ++b) {
        const float* xb  = reg_feat + (size_t)b * CI * HI * WI;
        const float* flb = flow     + (size_t)b * 2 * HO * WO;
        float*       ob  = out      + (size_t)b * 2 * HO * WO;
        kA<<<512, 256, 0, stream>>>(xb, wt, bt, f0p);
        kB<<<1024, 256, 0, stream>>>(f0p, wpB, b1p, f1p);
        kPad<<<(2 * FP_W * FP_W + 255) / 256, 256, 0, stream>>>(flb, flowp);
        kC<<<2048, 256, 0, stream>>>(f1p, wpC, b2p, flowp, ob);
    }
}

// Round 6
// 556.920 us; speedup vs baseline: 3.8596x; 1.1413x over previous
//
#include <hip/hip_runtime.h>

constexpr int HI = 256, WI = 256;   // reg_feat spatial
constexpr int HO = 512, WO = 512;   // upsampled spatial
constexpr int CI = 32;              // feat channels
constexpr int CK = 49;              // 7x7 unfold channels

// ---- ws layout (float offsets) --------------------------------------------
constexpr size_t OFF_WPC = 0;        // w2 frags: 13*2*4*64 uint4 = 26624 f32
constexpr size_t OFF_B2P = 26624;    // padded b2 [64]
constexpr size_t OFF_WPB = 26688;    // w1 frags: 7*2*4*64 uint4 = 14336 f32
constexpr size_t OFF_B1P = 41024;    // padded b1 [64]
constexpr size_t OFF_WPA = 41088;    // wt frags: 4cls*4tap*2s*2mf*64 uint4 = 16384 f32
constexpr size_t OFF_F0  = 57472;    // f0p u32 [512][512][32] (flowp aliases this)
constexpr size_t OFF_F1  = OFF_F0 + (size_t)HO * WO * CI;   // f1p u32 [49][512][512]
// xpp (padded packed x, [258][258][32] u32 = 2.13M) aliases the head of f1p:
// written by kPre, consumed by kA, dead before kB writes f1p.

constexpr int FP_W = 518;            // padded flow row (512 + 3 + 3)
constexpr int XP_W = 258;            // padded x row (256 + 1 + 1)

using bf16x8 = __attribute__((ext_vector_type(8))) short;
using f32x4  = __attribute__((ext_vector_type(4))) float;

__device__ inline unsigned bf_rne(float x) {           // fp32 -> bf16 bits (RNE)
    unsigned u = __float_as_uint(x);
    return (u + 0x7FFFu + ((u >> 16) & 1u)) >> 16;
}
__device__ inline unsigned pack_split(float v) {       // (hi<<16)|lo split-bf16
    const unsigned hi = bf_rne(v);
    const float vh = __uint_as_float(hi << 16);
    const unsigned lo = bf_rne(v - vh);
    return (hi << 16) | lo;
}

union FragU { uint4 q; bf16x8 v; unsigned u[4]; };

// v_perm selectors (validated R4/R5): from packed pair (v1,v0) build hi/lo planes
constexpr unsigned PERM_HI = 0x07060302u;
constexpr unsigned PERM_LO = 0x05040100u;

// ---------------------------------------------------------------------------
// kPre: x[32][256][256] f32 -> xpp[yp][xp][i] packed split-bf16 u32,
// zero-padded border (yp,xp in [0,258), real index -1). Kills all bounds
// checks in kA.
// ---------------------------------------------------------------------------
__global__ void kPre(const float* __restrict__ x, unsigned* __restrict__ xpp)
{
    const int yp = blockIdx.x;          // 0..257
    const int y  = yp - 1;
    for (int xpc = threadIdx.x; xpc < XP_W; xpc += 256) {
        const int xc = xpc - 1;
        uint4* dst = reinterpret_cast<uint4*>(xpp + ((size_t)yp * XP_W + xpc) * 32);
        if ((unsigned)y < 256u && (unsigned)xc < 256u) {
            const float* src = x + y * 256 + xc;
            #pragma unroll
            for (int r = 0; r < 8; ++r) {
                uint4 q;
                q.x = pack_split(src[(size_t)(4 * r + 0) * 65536]);
                q.y = pack_split(src[(size_t)(4 * r + 1) * 65536]);
                q.z = pack_split(src[(size_t)(4 * r + 2) * 65536]);
                q.w = pack_split(src[(size_t)(4 * r + 3) * 65536]);
                dst[r] = q;
            }
        } else {
            #pragma unroll
            for (int r = 0; r < 8; ++r) dst[r] = make_uint4(0u, 0u, 0u, 0u);
        }
    }
}

// ---------------------------------------------------------------------------
// repack: A-fragments for kA (4 parity classes x 4 taps), kB (chunk=t, k=i),
// kC (chunk c: kg=4c+g, oct=kg/7, t=kg%7, i=oct*8+j); split bf16 hi/lo.
// A-frag convention (verified R3-R5): lane l elem j -> A[mf*16+(l&15)][(l>>4)*8+j]
// ---------------------------------------------------------------------------
__global__ void repack(const float* __restrict__ wt,
                       const float* __restrict__ w1, const float* __restrict__ b1,
                       const float* __restrict__ w2, const float* __restrict__ b2,
                       uint4* __restrict__ wpA, uint4* __restrict__ wpB,
                       float* __restrict__ b1p, uint4* __restrict__ wpC,
                       float* __restrict__ b2p)
{
    const int j = blockIdx.x * 256 + threadIdx.x;
    if (j < 64) {
        b2p[j] = (j < CK) ? b2[j] : 1e18f;
        b1p[j] = (j < CK) ? b1[j] : 0.f;
    }
    if (j < 4 * 4 * 2 * 2 * 64) {           // kA: idx = (((cls*4+tap)*2+s)*2+mf)*64+lane
        const int lane = j & 63;
        const int mf   = (j >> 6) & 1;
        const int s    = (j >> 7) & 1;
        const int tap  = (j >> 8) & 3;
        const int cls  = j >> 10;           // ohpar*2 + owpar
        const int ohpar = cls >> 1, par = cls & 1;
        const int a = tap >> 1, d = tap & 1;
        const int kh = (ohpar ? 0 : 1) + 2 * a;
        const int kw = (par ? 0 : 1) + 2 * d;
        const int o = mf * 16 + (lane & 15);
        unsigned b[8];
        #pragma unroll
        for (int jj = 0; jj < 8; ++jj) {
            const int i = (lane >> 4) * 8 + jj;
            const float v = wt[((i * 32 + o) * 4 + kh) * 4 + kw];
            const unsigned hi = bf_rne(v);
            b[jj] = (s == 0) ? hi : bf_rne(v - __uint_as_float(hi << 16));
        }
        uint4 q;
        q.x = (b[1] << 16) | b[0];
        q.y = (b[3] << 16) | b[2];
        q.z = (b[5] << 16) | b[4];
        q.w = (b[7] << 16) | b[6];
        wpA[j] = q;
    }
    if (j < 7 * 2 * 4 * 64) {               // kB: chunk t, k = i
        const int t    = j >> 9;
        const int s    = (j >> 8) & 1;
        const int mf   = (j >> 6) & 3;
        const int lane = j & 63;
        const int o = mf * 16 + (lane & 15);
        unsigned b[8];
        #pragma unroll
        for (int jj = 0; jj < 8; ++jj) {
            const int i = (lane >> 4) * 8 + jj;
            float v = (o < CK) ? w1[o * 224 + i * 7 + t] : 0.f;
            const unsigned hi = bf_rne(v);
            b[jj] = (s == 0) ? hi : bf_rne(v - __uint_as_float(hi << 16));
        }
        uint4 q;
        q.x = (b[1] << 16) | b[0];
        q.y = (b[3] << 16) | b[2];
        q.z = (b[5] << 16) | b[4];
        q.w = (b[7] << 16) | b[6];
        wpB[((t * 2 + s) * 4 + mf) * 64 + lane] = q;
    }
    if (j < 13 * 2 * 4 * 64) {              // kC: kg=4c+g -> (oct,t); i=oct*8+jj
        const int c    = j >> 9;
        const int s    = (j >> 8) & 1;
        const int mf   = (j >> 6) & 3;
        const int lane = j & 63;
        const int o   = mf * 16 + (lane & 15);
        const int kg  = 4 * c + (lane >> 4);
        const int oct = kg / 7;
        const int t   = kg - 7 * oct;
        unsigned b[8];
        #pragma unroll
        for (int jj = 0; jj < 8; ++jj) {
            const int i = oct * 8 + jj;
            float v = 0.f;
            if (kg < CK && o < CK && i < CK) v = w2[o * 343 + i * 7 + t];
            const unsigned hi = bf_rne(v);
            b[jj] = (s == 0) ? hi : bf_rne(v - __uint_as_float(hi << 16));
        }
        uint4 q;
        q.x = (b[1] << 16) | b[0];
        q.y = (b[3] << 16) | b[2];
        q.z = (b[5] << 16) | b[4];
        q.w = (b[7] << 16) | b[6];
        wpC[((c * 2 + s) * 4 + mf) * 64 + lane] = q;
    }
}

// ---------------------------------------------------------------------------
// kPad: flowp[p][hh][ww] = flow[p][hh-3][ww-3], zero outside. [2][518][518]
// ---------------------------------------------------------------------------
__global__ void kPad(const float* __restrict__ flow, float* __restrict__ flowp)
{
    const int idx = blockIdx.x * 256 + threadIdx.x;
    if (idx >= 2 * FP_W * FP_W) return;
    const int p  = idx / (FP_W * FP_W);
    const int q  = idx - p * (FP_W * FP_W);
    const int hh = q / FP_W;
    const int ww = q - hh * FP_W;
    float v = 0.f;
    const int hs = hh - 3, ws = ww - 3;
    if ((unsigned)hs < (unsigned)HO && (unsigned)ws < (unsigned)WO)
        v = flow[p * (HO * WO) + hs * WO + ws];
    flowp[idx] = v;
}

// ---------------------------------------------------------------------------
// kA: ConvTranspose2d(32,32,4,s=2,p=1) via split-bf16 MFMA.
// Fixed parity class => 4 taps x K=32(i) = 4 chunks; M=32 ch (2 mf frags).
// Block = half output row (256 px); wave = 64 px of ONE parity.
// B-frags: 2x dwordx4 from padded xpp + v_perm (no bounds checks).
// Epilogue: wave-private LDS bounce -> per-pixel 128B contiguous stores.
// ---------------------------------------------------------------------------
__global__ __launch_bounds__(256, 4)
void kA(const unsigned* __restrict__ xpp, const uint4* __restrict__ wpA,
        const float* __restrict__ bt, unsigned* __restrict__ f0p)
{
    __shared__ unsigned ep[4][64 * 36];     // per-wave [px][ch] stride 36, 36.9 KB

    const int tid  = threadIdx.x;
    const int oh   = blockIdx.x >> 1;
    const int half = blockIdx.x & 1;
    const int wv   = tid >> 6;
    const int lane = tid & 63;
    const int col  = lane & 15;
    const int g    = lane >> 4;
    const int par  = wv >> 1;               // ow parity this wave computes
    const int n0   = half * 128 + (wv & 1) * 64;   // parity-local pixel base

    const int ohpar = oh & 1;
    const int kh0   = ohpar ? 0 : 1;
    const int ihA   = (oh + 1 - kh0) >> 1;
    const int cls   = ohpar * 2 + par;
    const int ioff  = par ? 2 : 1;          // padded-x col = n + ioff - d

    f32x4 acc[2][4];
    #pragma unroll
    for (int mf = 0; mf < 2; ++mf)
        #pragma unroll
        for (int nf = 0; nf < 4; ++nf)
            acc[mf][nf] = (f32x4){0.f, 0.f, 0.f, 0.f};

    #pragma unroll
    for (int a = 0; a < 2; ++a) {
        const int rowbase = (ihA + 1 - a) * XP_W;
        #pragma unroll
        for (int d = 0; d < 2; ++d) {
            bf16x8 Bh[4], Bl[4];
            #pragma unroll
            for (int nf = 0; nf < 4; ++nf) {
                const size_t base =
                    ((size_t)(rowbase + n0 + nf * 16 + col + ioff - d)) * 32 + g * 8;
                const uint4 q0 = *reinterpret_cast<const uint4*>(xpp + base);
                const uint4 q1 = *reinterpret_cast<const uint4*>(xpp + base + 4);
                const unsigned u[8] = {q0.x, q0.y, q0.z, q0.w, q1.x, q1.y, q1.z, q1.w};
                FragU fh, fl;
                #pragma unroll
                for (int r = 0; r < 4; ++r) {
                    fh.u[r] = __builtin_amdgcn_perm(u[2 * r + 1], u[2 * r], PERM_HI);
                    fl.u[r] = __builtin_amdgcn_perm(u[2 * r + 1], u[2 * r], PERM_LO);
                }
                Bh[nf] = fh.v;
                Bl[nf] = fl.v;
            }
            const int tap = a * 2 + d;
            #pragma unroll
            for (int mf = 0; mf < 2; ++mf) {
                FragU ah, al;
                ah.q = wpA[(((cls * 4 + tap) * 2 + 0) * 2 + mf) * 64 + lane];
                al.q = wpA[(((cls * 4 + tap) * 2 + 1) * 2 + mf) * 64 + lane];
                #pragma unroll
                for (int nf = 0; nf < 4; ++nf) {
                    acc[mf][nf] = __builtin_amdgcn_mfma_f32_16x16x32_bf16(ah.v, Bh[nf], acc[mf][nf], 0, 0, 0);
                    acc[mf][nf] = __builtin_amdgcn_mfma_f32_16x16x32_bf16(ah.v, Bl[nf], acc[mf][nf], 0, 0, 0);
                    acc[mf][nf] = __builtin_amdgcn_mfma_f32_16x16x32_bf16(al.v, Bh[nf], acc[mf][nf], 0, 0, 0);
                }
            }
        }
    }

    // epilogue: bias, pack, LDS transpose (wave-private), contiguous store
    unsigned* myep = ep[wv];
    #pragma unroll
    for (int mf = 0; mf < 2; ++mf)
        #pragma unroll
        for (int r = 0; r < 4; ++r) {
            const int ch = mf * 16 + g * 4 + r;
            const float bv = bt[ch];
            #pragma unroll
            for (int nf = 0; nf < 4; ++nf)
                myep[(nf * 16 + col) * 36 + ch] = pack_split(acc[mf][nf][r] + bv);
        }
    // same-wave LDS RAW: compiler orders via lgkmcnt (may-alias); no barrier needed

    const int ow = 2 * (n0 + lane) + par;
    uint4* dst = reinterpret_cast<uint4*>(f0p + ((size_t)oh * WO + ow) * 32);
    const uint4* src = reinterpret_cast<const uint4*>(myep + lane * 36);
    #pragma unroll
    for (int u = 0; u < 8; ++u) dst[u] = src[u];
}

// ---------------------------------------------------------------------------
// kB: 7x1 vertical conv 32->49 via split-bf16 MFMA. No LDS.
// ---------------------------------------------------------------------------
__global__ __launch_bounds__(256, 3)
void kB(const unsigned* __restrict__ f0p, const uint4* __restrict__ wpB,
        const float* __restrict__ b1p, unsigned* __restrict__ f1p)
{
    const int tid  = threadIdx.x;
    const int h    = blockIdx.x >> 1;
    const int lane = tid & 63;
    const int n    = lane & 15;
    const int g    = lane >> 4;
    const int w0   = ((blockIdx.x & 1) << 8) + ((tid >> 6) << 6);  // wave col base

    f32x4 acc[4][4];
    #pragma unroll
    for (int mf = 0; mf < 4; ++mf)
        #pragma unroll
        for (int nf = 0; nf < 4; ++nf)
            acc[mf][nf] = (f32x4){0.f, 0.f, 0.f, 0.f};

    #pragma unroll
    for (int t = 0; t < 7; ++t) {
        const int hr = h + t - 3;
        if ((unsigned)hr < (unsigned)HO) {
            bf16x8 Bh[4], Bl[4];
            #pragma unroll
            for (int nf = 0; nf < 4; ++nf) {
                const size_t base = ((size_t)hr * WO + (w0 + nf * 16 + n)) * 32 + g * 8;
                const uint4 q0 = *reinterpret_cast<const uint4*>(f0p + base);
                const uint4 q1 = *reinterpret_cast<const uint4*>(f0p + base + 4);
                const unsigned u[8] = {q0.x, q0.y, q0.z, q0.w, q1.x, q1.y, q1.z, q1.w};
                FragU fh, fl;
                #pragma unroll
                for (int r = 0; r < 4; ++r) {
                    fh.u[r] = __builtin_amdgcn_perm(u[2 * r + 1], u[2 * r], PERM_HI);
                    fl.u[r] = __builtin_amdgcn_perm(u[2 * r + 1], u[2 * r], PERM_LO);
                }
                Bh[nf] = fh.v;
                Bl[nf] = fl.v;
            }
            #pragma unroll
            for (int mf = 0; mf < 4; ++mf) {
                FragU ah, al;
                ah.q = wpB[((t * 2 + 0) * 4 + mf) * 64 + lane];
                al.q = wpB[((t * 2 + 1) * 4 + mf) * 64 + lane];
                #pragma unroll
                for (int nf = 0; nf < 4; ++nf) {
                    acc[mf][nf] = __builtin_amdgcn_mfma_f32_16x16x32_bf16(ah.v, Bh[nf], acc[mf][nf], 0, 0, 0);
                    acc[mf][nf] = __builtin_amdgcn_mfma_f32_16x16x32_bf16(ah.v, Bl[nf], acc[mf][nf], 0, 0, 0);
                    acc[mf][nf] = __builtin_amdgcn_mfma_f32_16x16x32_bf16(al.v, Bh[nf], acc[mf][nf], 0, 0, 0);
                }
            }
        }
    }

    #pragma unroll
    for (int mf = 0; mf < 4; ++mf)
        #pragma unroll
        for (int r = 0; r < 4; ++r) {
            const int o = mf * 16 + g * 4 + r;
            if (o < CK) {
                const float bv = b1p[o];
                #pragma unroll
                for (int nf = 0; nf < 4; ++nf) {
                    const int w = w0 + nf * 16 + n;
                    f1p[((size_t)o * HO + h) * WO + w] = pack_split(acc[mf][nf][r] + bv);
                }
            }
        }
}

// ---------------------------------------------------------------------------
// kC: 1x7 conv 49->49 via split-bf16 MFMA + softmax + flow average.
// 128-px strips. LDS: transposed hi/lo planes; B-frag = ONE ds_read_b128.
// ---------------------------------------------------------------------------
__global__ __launch_bounds__(256, 4)
void kC(const unsigned* __restrict__ f1p, const uint4* __restrict__ wpC,
        const float* __restrict__ b2p, const float* __restrict__ flowp,
        float* __restrict__ out)
{
    __shared__ uint4 Lh4[134 * 7];          // hi-plane, rows of 7 uint4 (56 bf16)
    __shared__ uint4 Ll4[134 * 7];          // lo-plane
    unsigned* Lh = reinterpret_cast<unsigned*>(Lh4);
    unsigned* Ll = reinterpret_cast<unsigned*>(Ll4);

    const int tid = threadIdx.x;
    const int h   = blockIdx.x >> 2;
    const int w0  = (blockIdx.x & 3) << 7;

    for (int idx = tid; idx < 24 * 134; idx += 256) {
        const int ip = idx / 134;
        const int q  = idx - ip * 134;
        const int ww = w0 - 3 + q;
        unsigned v0 = 0u, v1 = 0u;
        if ((unsigned)ww < (unsigned)WO) {
            v0 = f1p[((size_t)(2 * ip) * HO + h) * WO + ww];
            v1 = f1p[((size_t)(2 * ip + 1) * HO + h) * WO + ww];
        }
        Lh[q * 28 + ip] = __builtin_amdgcn_perm(v1, v0, PERM_HI);
        Ll[q * 28 + ip] = __builtin_amdgcn_perm(v1, v0, PERM_LO);
    }
    for (int idx = tid; idx < 134 * 4; idx += 256) {
        const int q  = idx >> 2;
        const int p4 = idx & 3;
        unsigned hw = 0u, lw = 0u;
        if (p4 == 0) {
            const int ww = w0 - 3 + q;
            unsigned v0 = 0u;
            if ((unsigned)ww < (unsigned)WO)
                v0 = f1p[((size_t)48 * HO + h) * WO + ww];
            hw = v0 >> 16;
            lw = v0 & 0xFFFFu;
        }
        Lh[q * 28 + 24 + p4] = hw;
        Ll[q * 28 + 24 + p4] = lw;
    }
    __syncthreads();

    const int wv   = tid >> 6;
    const int lane = tid & 63;
    const int col  = lane & 15;
    const int g    = lane >> 4;
    const int pw   = wv << 5;
    const int pix  = pw + col;

    f32x4 acc[4][2];
    #pragma unroll
    for (int mf = 0; mf < 4; ++mf) {
        acc[mf][0] = (f32x4){0.f, 0.f, 0.f, 0.f};
        acc[mf][1] = (f32x4){0.f, 0.f, 0.f, 0.f};
    }

    #pragma unroll
    for (int c = 0; c < 13; ++c) {
        const int kg  = 4 * c + g;
        const int oct = (kg * 37) >> 8;
        const int t   = kg - 7 * oct;
        const int bq  = (pix + t) * 7 + oct;
        FragU bh0, bl0, bh1, bl1;
        bh0.q = Lh4[bq];        bl0.q = Ll4[bq];
        bh1.q = Lh4[bq + 112];  bl1.q = Ll4[bq + 112];
        #pragma unroll
        for (int mf = 0; mf < 4; ++mf) {
            FragU ah, al;
            ah.q = wpC[((c * 2 + 0) * 4 + mf) * 64 + lane];
            al.q = wpC[((c * 2 + 1) * 4 + mf) * 64 + lane];
            acc[mf][0] = __builtin_amdgcn_mfma_f32_16x16x32_bf16(ah.v, bh0.v, acc[mf][0], 0, 0, 0);
            acc[mf][0] = __builtin_amdgcn_mfma_f32_16x16x32_bf16(ah.v, bl0.v, acc[mf][0], 0, 0, 0);
            acc[mf][0] = __builtin_amdgcn_mfma_f32_16x16x32_bf16(al.v, bh0.v, acc[mf][0], 0, 0, 0);
            acc[mf][1] = __builtin_amdgcn_mfma_f32_16x16x32_bf16(ah.v, bh1.v, acc[mf][1], 0, 0, 0);
            acc[mf][1] = __builtin_amdgcn_mfma_f32_16x16x32_bf16(ah.v, bl1.v, acc[mf][1], 0, 0, 0);
            acc[mf][1] = __builtin_amdgcn_mfma_f32_16x16x32_bf16(al.v, bh1.v, acc[mf][1], 0, 0, 0);
        }
    }

    float bb[16];
    #pragma unroll
    for (int mf = 0; mf < 4; ++mf)
        #pragma unroll
        for (int r = 0; r < 4; ++r)
            bb[mf * 4 + r] = b2p[mf * 16 + g * 4 + r];

    #pragma unroll
    for (int mf = 0; mf < 4; ++mf)
        #pragma unroll
        for (int nf = 0; nf < 2; ++nf)
            #pragma unroll
            for (int r = 0; r < 4; ++r) {
                const float f = acc[mf][nf][r] + bb[mf * 4 + r];
                acc[mf][nf][r] = f * f;
            }

    float pm[2];
    #pragma unroll
    for (int nf = 0; nf < 2; ++nf) {
        float m = acc[0][nf][0];
        #pragma unroll
        for (int mf = 0; mf < 4; ++mf)
            #pragma unroll
            for (int r = 0; r < 4; ++r)
                m = fminf(m, acc[mf][nf][r]);
        m = fminf(m, __shfl_xor(m, 16));
        m = fminf(m, __shfl_xor(m, 32));
        pm[nf] = m;
    }

    const float* fpx = flowp + (size_t)h * FP_W + (w0 + pw + col);
    const float* fpy = fpx + (size_t)FP_W * FP_W;
    float sx[2] = {0.f, 0.f};
    float sy[2] = {0.f, 0.f};
    float dv[2] = {0.f, 0.f};

    #pragma unroll
    for (int mf = 0; mf < 4; ++mf) {
        #pragma unroll
        for (int r = 0; r < 4; ++r) {
            const int ch = mf * 16 + g * 4 + r;
            int ki = (ch * 37) >> 8;
            int kj = ch - 7 * ki;
            ki = min(ki, 6);
            kj = min(kj, 6);
            const int off = ki * FP_W + kj;
            #pragma unroll
            for (int nf = 0; nf < 2; ++nf) {
                const float d = __expf(pm[nf] - acc[mf][nf][r]);
                dv[nf] += d;
                sx[nf] += d * fpx[off + nf * 16];
                sy[nf] += d * fpy[off + nf * 16];
            }
        }
    }

    #pragma unroll
    for (int nf = 0; nf < 2; ++nf) {
        float d = dv[nf], x = sx[nf], y = sy[nf];
        d += __shfl_xor(d, 16);  x += __shfl_xor(x, 16);  y += __shfl_xor(y, 16);
        d += __shfl_xor(d, 32);  x += __shfl_xor(x, 32);  y += __shfl_xor(y, 32);
        if (g == 0) {
            const int w = w0 + pw + nf * 16 + col;
            out[(size_t)h * WO + w]                     = x / d;
            out[(size_t)HO * WO + (size_t)h * WO + w]   = y / d;
        }
    }
}

// ---------------------------------------------------------------------------
extern "C" void kernel_launch(void* const* d_in, const int* in_sizes, int n_in,
                              void* d_out, int out_size, void* d_ws, size_t ws_size,
                              hipStream_t stream) {
    const float* reg_feat = (const float*)d_in[0];
    const float* flow     = (const float*)d_in[1];
    const float* wt       = (const float*)d_in[2];
    const float* bt       = (const float*)d_in[3];
    const float* w1       = (const float*)d_in[4];
    const float* b1       = (const float*)d_in[5];
    const float* w2       = (const float*)d_in[6];
    const float* b2       = (const float*)d_in[7];
    float* out = (float*)d_out;
    (void)in_sizes; (void)n_in; (void)out_size; (void)ws_size;

    float*    ws    = (float*)d_ws;
    uint4*    wpC   = (uint4*)(ws + OFF_WPC);
    float*    b2p   = ws + OFF_B2P;
    uint4*    wpB   = (uint4*)(ws + OFF_WPB);
    float*    b1p   = ws + OFF_B1P;
    uint4*    wpA   = (uint4*)(ws + OFF_WPA);
    unsigned* f0p   = (unsigned*)(ws + OFF_F0);
    float*    flowp = ws + OFF_F0;          // aliases f0p: written after kB reads it
    unsigned* f1p   = (unsigned*)(ws + OFF_F1);
    unsigned* xpp   = f1p;                  // aliases f1p head: dead before kB writes

    repack<<<26, 256, 0, stream>>>(wt, w1, b1, w2, b2, wpA, wpB, b1p, wpC, b2p);

    for (int b = 0; b < 4; ++b) {
        const float* xb  = reg_feat + (size_t)b * CI * HI * WI;
        const float* flb = flow     + (size_t)b * 2 * HO * WO;
        float*       ob  = out      + (size_t)b * 2 * HO * WO;
        kPre<<<XP_W, 256, 0, stream>>>(xb, xpp);
        kA<<<1024, 256, 0, stream>>>(xpp, wpA, bt, f0p);
        kB<<<1024, 256, 0, stream>>>(f0p, wpB, b1p, f1p);
        kPad<<<(2 * FP_W * FP_W + 255) / 256, 256, 0, stream>>>(flb, flowp);
        kC<<<2048, 256, 0, stream>>>(f1p, wpC, b2p, flowp, ob);
    }
}

// Round 8
// 487.753 us; speedup vs baseline: 4.4069x; 1.1418x over previous
//
#include <hip/hip_runtime.h>

constexpr int HI = 256, WI = 256;   // reg_feat spatial
constexpr int HO = 512, WO = 512;   // upsampled spatial
constexpr int CI = 32;              // feat channels
constexpr int CK = 49;              // 7x7 unfold channels

// ---- ws layout (float offsets) --------------------------------------------
constexpr size_t OFF_WPC = 0;        // w2 frags: 13*2*4*64 uint4 = 26624 f32
constexpr size_t OFF_B2P = 26624;    // padded b2 [64]
constexpr size_t OFF_WPB = 26688;    // w1 frags: 7*2*4*64 uint4 = 14336 f32
constexpr size_t OFF_B1P = 41024;    // padded b1 [64]
constexpr size_t OFF_WPA = 41088;    // wt frags: 4cls*4tap*2s*2mf*64 uint4 = 16384 f32
constexpr size_t OFF_F0  = 57472;    // f0p u32 [512][512][32]
constexpr size_t OFF_XPP = OFF_F0 + (size_t)HO * WO * CI;      // xpp u32 [258][258][32]
constexpr size_t OFF_FLP = OFF_XPP + (size_t)258 * 258 * 32;   // flowp f32 [2][518][518]

constexpr int FP_W = 518;            // padded flow row (512 + 3 + 3)
constexpr int XP_W = 258;            // padded x row (256 + 1 + 1)

using bf16x8 = __attribute__((ext_vector_type(8))) short;
using f32x4  = __attribute__((ext_vector_type(4))) float;

__device__ inline unsigned bf_rne(float x) {           // fp32 -> bf16 bits (RNE)
    unsigned u = __float_as_uint(x);
    return (u + 0x7FFFu + ((u >> 16) & 1u)) >> 16;
}
__device__ inline unsigned pack_split(float v) {       // (hi<<16)|lo split-bf16
    const unsigned hi = bf_rne(v);
    const float vh = __uint_as_float(hi << 16);
    const unsigned lo = bf_rne(v - vh);
    return (hi << 16) | lo;
}

union FragU { uint4 q; bf16x8 v; unsigned u[4]; };

// v_perm selectors (validated R4-R6)
constexpr unsigned PERM_HI = 0x07060302u;
constexpr unsigned PERM_LO = 0x05040100u;

// ---------------------------------------------------------------------------
// kPP: fused padding kernel.
//  part 1 (bid < 258): x[32][256][256] f32 -> xpp[yp][xp][i] packed u32, 0-border
//  part 2: flowp[p][hh][ww] = flow[p][hh-3][ww-3], zero outside. [2][518][518]
// ---------------------------------------------------------------------------
__global__ void kPP(const float* __restrict__ x, const float* __restrict__ flow,
                    unsigned* __restrict__ xpp, float* __restrict__ flowp)
{
    const int bid = blockIdx.x;
    if (bid < XP_W) {
        const int yp = bid;
        const int y  = yp - 1;
        for (int xpc = threadIdx.x; xpc < XP_W; xpc += 256) {
            const int xc = xpc - 1;
            uint4* dst = reinterpret_cast<uint4*>(xpp + ((size_t)yp * XP_W + xpc) * 32);
            if ((unsigned)y < 256u && (unsigned)xc < 256u) {
                const float* src = x + y * 256 + xc;
                #pragma unroll
                for (int r = 0; r < 8; ++r) {
                    uint4 q;
                    q.x = pack_split(src[(size_t)(4 * r + 0) * 65536]);
                    q.y = pack_split(src[(size_t)(4 * r + 1) * 65536]);
                    q.z = pack_split(src[(size_t)(4 * r + 2) * 65536]);
                    q.w = pack_split(src[(size_t)(4 * r + 3) * 65536]);
                    dst[r] = q;
                }
            } else {
                #pragma unroll
                for (int r = 0; r < 8; ++r) dst[r] = make_uint4(0u, 0u, 0u, 0u);
            }
        }
    } else {
        const int idx = (bid - XP_W) * 256 + threadIdx.x;
        if (idx >= 2 * FP_W * FP_W) return;
        const int p  = idx / (FP_W * FP_W);
        const int q  = idx - p * (FP_W * FP_W);
        const int hh = q / FP_W;
        const int ww = q - hh * FP_W;
        float v = 0.f;
        const int hs = hh - 3, wsx = ww - 3;
        if ((unsigned)hs < (unsigned)HO && (unsigned)wsx < (unsigned)WO)
            v = flow[p * (HO * WO) + hs * WO + wsx];
        flowp[idx] = v;
    }
}

// ---------------------------------------------------------------------------
// repack: A-fragments for kA (4 parity classes x 4 taps), kBC stage-1
// (chunk=t, k=i) and stage-2 (chunk c: kg=4c+g, oct=kg/7, t=kg%7, i=oct*8+j);
// split bf16 hi/lo. A-frag: lane l elem j -> A[mf*16+(l&15)][(l>>4)*8+j].
// ---------------------------------------------------------------------------
__global__ void repack(const float* __restrict__ wt,
                       const float* __restrict__ w1, const float* __restrict__ b1,
                       const float* __restrict__ w2, const float* __restrict__ b2,
                       uint4* __restrict__ wpA, uint4* __restrict__ wpB,
                       float* __restrict__ b1p, uint4* __restrict__ wpC,
                       float* __restrict__ b2p)
{
    const int j = blockIdx.x * 256 + threadIdx.x;
    if (j < 64) {
        b2p[j] = (j < CK) ? b2[j] : 1e18f;
        b1p[j] = (j < CK) ? b1[j] : 0.f;
    }
    if (j < 4 * 4 * 2 * 2 * 64) {           // kA
        const int lane = j & 63;
        const int mf   = (j >> 6) & 1;
        const int s    = (j >> 7) & 1;
        const int tap  = (j >> 8) & 3;
        const int cls  = j >> 10;
        const int ohpar = cls >> 1, par = cls & 1;
        const int a = tap >> 1, d = tap & 1;
        const int kh = (ohpar ? 0 : 1) + 2 * a;
        const int kw = (par ? 0 : 1) + 2 * d;
        const int o = mf * 16 + (lane & 15);
        unsigned b[8];
        #pragma unroll
        for (int jj = 0; jj < 8; ++jj) {
            const int i = (lane >> 4) * 8 + jj;
            const float v = wt[((i * 32 + o) * 4 + kh) * 4 + kw];
            const unsigned hi = bf_rne(v);
            b[jj] = (s == 0) ? hi : bf_rne(v - __uint_as_float(hi << 16));
        }
        uint4 q;
        q.x = (b[1] << 16) | b[0];
        q.y = (b[3] << 16) | b[2];
        q.z = (b[5] << 16) | b[4];
        q.w = (b[7] << 16) | b[6];
        wpA[j] = q;
    }
    if (j < 7 * 2 * 4 * 64) {               // stage-1: chunk t, k = i
        const int t    = j >> 9;
        const int s    = (j >> 8) & 1;
        const int mf   = (j >> 6) & 3;
        const int lane = j & 63;
        const int o = mf * 16 + (lane & 15);
        unsigned b[8];
        #pragma unroll
        for (int jj = 0; jj < 8; ++jj) {
            const int i = (lane >> 4) * 8 + jj;
            float v = (o < CK) ? w1[o * 224 + i * 7 + t] : 0.f;
            const unsigned hi = bf_rne(v);
            b[jj] = (s == 0) ? hi : bf_rne(v - __uint_as_float(hi << 16));
        }
        uint4 q;
        q.x = (b[1] << 16) | b[0];
        q.y = (b[3] << 16) | b[2];
        q.z = (b[5] << 16) | b[4];
        q.w = (b[7] << 16) | b[6];
        wpB[((t * 2 + s) * 4 + mf) * 64 + lane] = q;
    }
    if (j < 13 * 2 * 4 * 64) {              // stage-2: kg=4c+g -> (oct,t); i=oct*8+jj
        const int c    = j >> 9;
        const int s    = (j >> 8) & 1;
        const int mf   = (j >> 6) & 3;
        const int lane = j & 63;
        const int o   = mf * 16 + (lane & 15);
        const int kg  = 4 * c + (lane >> 4);
        const int oct = kg / 7;
        const int t   = kg - 7 * oct;
        unsigned b[8];
        #pragma unroll
        for (int jj = 0; jj < 8; ++jj) {
            const int i = oct * 8 + jj;
            float v = 0.f;
            if (kg < CK && o < CK && i < CK) v = w2[o * 343 + i * 7 + t];
            const unsigned hi = bf_rne(v);
            b[jj] = (s == 0) ? hi : bf_rne(v - __uint_as_float(hi << 16));
        }
        uint4 q;
        q.x = (b[1] << 16) | b[0];
        q.y = (b[3] << 16) | b[2];
        q.z = (b[5] << 16) | b[4];
        q.w = (b[7] << 16) | b[6];
        wpC[((c * 2 + s) * 4 + mf) * 64 + lane] = q;
    }
}

// ---------------------------------------------------------------------------
// kA: ConvTranspose2d(32,32,4,s=2,p=1) via split-bf16 MFMA (unchanged R6).
// ---------------------------------------------------------------------------
__global__ __launch_bounds__(256, 4)
void kA(const unsigned* __restrict__ xpp, const uint4* __restrict__ wpA,
        const float* __restrict__ bt, unsigned* __restrict__ f0p)
{
    __shared__ unsigned ep[4][64 * 36];

    const int tid  = threadIdx.x;
    const int oh   = blockIdx.x >> 1;
    const int half = blockIdx.x & 1;
    const int wv   = tid >> 6;
    const int lane = tid & 63;
    const int col  = lane & 15;
    const int g    = lane >> 4;
    const int par  = wv >> 1;
    const int n0   = half * 128 + (wv & 1) * 64;

    const int ohpar = oh & 1;
    const int kh0   = ohpar ? 0 : 1;
    const int ihA   = (oh + 1 - kh0) >> 1;
    const int cls   = ohpar * 2 + par;
    const int ioff  = par ? 2 : 1;

    f32x4 acc[2][4];
    #pragma unroll
    for (int mf = 0; mf < 2; ++mf)
        #pragma unroll
        for (int nf = 0; nf < 4; ++nf)
            acc[mf][nf] = (f32x4){0.f, 0.f, 0.f, 0.f};

    #pragma unroll
    for (int a = 0; a < 2; ++a) {
        const int rowbase = (ihA + 1 - a) * XP_W;
        #pragma unroll
        for (int d = 0; d < 2; ++d) {
            bf16x8 Bh[4], Bl[4];
            #pragma unroll
            for (int nf = 0; nf < 4; ++nf) {
                const size_t base =
                    ((size_t)(rowbase + n0 + nf * 16 + col + ioff - d)) * 32 + g * 8;
                const uint4 q0 = *reinterpret_cast<const uint4*>(xpp + base);
                const uint4 q1 = *reinterpret_cast<const uint4*>(xpp + base + 4);
                const unsigned u[8] = {q0.x, q0.y, q0.z, q0.w, q1.x, q1.y, q1.z, q1.w};
                FragU fh, fl;
                #pragma unroll
                for (int r = 0; r < 4; ++r) {
                    fh.u[r] = __builtin_amdgcn_perm(u[2 * r + 1], u[2 * r], PERM_HI);
                    fl.u[r] = __builtin_amdgcn_perm(u[2 * r + 1], u[2 * r], PERM_LO);
                }
                Bh[nf] = fh.v;
                Bl[nf] = fl.v;
            }
            const int tap = a * 2 + d;
            #pragma unroll
            for (int mf = 0; mf < 2; ++mf) {
                FragU ah, al;
                ah.q = wpA[(((cls * 4 + tap) * 2 + 0) * 2 + mf) * 64 + lane];
                al.q = wpA[(((cls * 4 + tap) * 2 + 1) * 2 + mf) * 64 + lane];
                #pragma unroll
                for (int nf = 0; nf < 4; ++nf) {
                    acc[mf][nf] = __builtin_amdgcn_mfma_f32_16x16x32_bf16(ah.v, Bh[nf], acc[mf][nf], 0, 0, 0);
                    acc[mf][nf] = __builtin_amdgcn_mfma_f32_16x16x32_bf16(ah.v, Bl[nf], acc[mf][nf], 0, 0, 0);
                    acc[mf][nf] = __builtin_amdgcn_mfma_f32_16x16x32_bf16(al.v, Bh[nf], acc[mf][nf], 0, 0, 0);
                }
            }
        }
    }

    unsigned* myep = ep[wv];
    #pragma unroll
    for (int mf = 0; mf < 2; ++mf)
        #pragma unroll
        for (int r = 0; r < 4; ++r) {
            const int ch = mf * 16 + g * 4 + r;
            const float bv = bt[ch];
            #pragma unroll
            for (int nf = 0; nf < 4; ++nf)
                myep[(nf * 16 + col) * 36 + ch] = pack_split(acc[mf][nf][r] + bv);
        }

    const int ow = 2 * (n0 + lane) + par;
    uint4* dst = reinterpret_cast<uint4*>(f0p + ((size_t)oh * WO + ow) * 32);
    const uint4* src = reinterpret_cast<const uint4*>(myep + lane * 36);
    #pragma unroll
    for (int u = 0; u < 8; ++u) dst[u] = src[u];
}

// ---------------------------------------------------------------------------
// kBC: FUSED stage B (7x1 conv 32->49) + stage C (1x7 conv 49->49 + softmax +
// flow average). Block = 128-px strip of one row h; grid 2048, XCD-swizzled.
// Stage 1: 9 x 16-px frags (cols w0-3 .. w0+140) -> f1 row directly into
// transposed hi/lo LDS planes. OUT-OF-IMAGE COLUMNS STORE ZERO (the 1x7
// conv's horizontal zero-padding — R7 bug was storing b1 there).
// Stage 2: identical to R6 kC minus its global staging.
// ---------------------------------------------------------------------------
__global__ __launch_bounds__(256, 4)
void kBC(const unsigned* __restrict__ f0p, const uint4* __restrict__ wpB,
         const float* __restrict__ b1p, const uint4* __restrict__ wpC,
         const float* __restrict__ b2p, const float* __restrict__ flowp,
         float* __restrict__ out)
{
    __shared__ uint4 Lh4[134 * 7];          // hi-plane, rows of 7 uint4 (56 ch)
    __shared__ uint4 Ll4[134 * 7];          // lo-plane
    unsigned* Lh = reinterpret_cast<unsigned*>(Lh4);
    unsigned* Ll = reinterpret_cast<unsigned*>(Ll4);

    // bijective XCD swizzle: 2048 blocks = 8 XCDs x 256 contiguous
    const int bid = ((blockIdx.x & 7) << 8) + (blockIdx.x >> 3);
    const int h   = bid >> 2;
    const int w0  = (bid & 3) << 7;

    const int tid  = threadIdx.x;
    const int wv   = tid >> 6;
    const int lane = tid & 63;
    const int col  = lane & 15;
    const int g    = lane >> 4;

    // ---- stage 1: f1 row h, cols w0-3 .. w0+140 (9 frags of 16) ------------
    const int nfr = (wv == 3) ? 3 : 2;
    const int fid0 = wv, fid1 = wv + 4, fid2 = 8;

    f32x4 acc1[3][4];
    #pragma unroll
    for (int fi = 0; fi < 3; ++fi)
        #pragma unroll
        for (int mf = 0; mf < 4; ++mf)
            acc1[fi][mf] = (f32x4){0.f, 0.f, 0.f, 0.f};

    #pragma unroll
    for (int t = 0; t < 7; ++t) {
        const int hr = h + t - 3;
        if ((unsigned)hr < (unsigned)HO) {
            FragU ah[4], al[4];
            #pragma unroll
            for (int mf = 0; mf < 4; ++mf) {
                ah[mf].q = wpB[((t * 2 + 0) * 4 + mf) * 64 + lane];
                al[mf].q = wpB[((t * 2 + 1) * 4 + mf) * 64 + lane];
            }
            #pragma unroll
            for (int fi = 0; fi < 3; ++fi) {
                if (fi < nfr) {
                    const int f  = (fi == 0) ? fid0 : (fi == 1) ? fid1 : fid2;
                    const int wc = w0 - 3 + f * 16 + col;
                    const int wcc = min(max(wc, 0), WO - 1);
                    const bool valid = ((unsigned)wc < (unsigned)WO);
                    const size_t base = ((size_t)hr * WO + wcc) * 32 + g * 8;
                    uint4 q0 = *reinterpret_cast<const uint4*>(f0p + base);
                    uint4 q1 = *reinterpret_cast<const uint4*>(f0p + base + 4);
                    if (!valid) { q0 = make_uint4(0,0,0,0); q1 = make_uint4(0,0,0,0); }
                    const unsigned u[8] = {q0.x, q0.y, q0.z, q0.w, q1.x, q1.y, q1.z, q1.w};
                    FragU fh, fl;
                    #pragma unroll
                    for (int r = 0; r < 4; ++r) {
                        fh.u[r] = __builtin_amdgcn_perm(u[2 * r + 1], u[2 * r], PERM_HI);
                        fl.u[r] = __builtin_amdgcn_perm(u[2 * r + 1], u[2 * r], PERM_LO);
                    }
                    #pragma unroll
                    for (int mf = 0; mf < 4; ++mf) {
                        acc1[fi][mf] = __builtin_amdgcn_mfma_f32_16x16x32_bf16(ah[mf].v, fh.v, acc1[fi][mf], 0, 0, 0);
                        acc1[fi][mf] = __builtin_amdgcn_mfma_f32_16x16x32_bf16(ah[mf].v, fl.v, acc1[fi][mf], 0, 0, 0);
                        acc1[fi][mf] = __builtin_amdgcn_mfma_f32_16x16x32_bf16(al[mf].v, fh.v, acc1[fi][mf], 0, 0, 0);
                    }
                }
            }
        }
    }

    // write f1 row into transposed planes: ch = mf*16+g*4+r, col q = f*16+col.
    // Out-of-image columns (wc outside [0,512)) must store ZERO — they are the
    // 1x7 conv's zero padding, not biased conv outputs.
    #pragma unroll
    for (int fi = 0; fi < 3; ++fi) {
        if (fi < nfr) {
            const int f = (fi == 0) ? fid0 : (fi == 1) ? fid1 : fid2;
            const int q = f * 16 + col;
            const int wc = w0 - 3 + q;
            const bool vcol = ((unsigned)wc < (unsigned)WO);
            if (q < 134) {
                #pragma unroll
                for (int mf = 0; mf < 4; ++mf) {
                    if (mf < 3 || g < 2) {          // ch 56..63 don't exist
                        const int chb = mf * 16 + g * 4;
                        unsigned hh[4], ll[4];
                        #pragma unroll
                        for (int r = 0; r < 4; ++r) {
                            const float v = vcol ? (acc1[fi][mf][r] + b1p[chb + r]) : 0.f;
                            hh[r] = bf_rne(v);
                            ll[r] = bf_rne(v - __uint_as_float(hh[r] << 16));
                        }
                        const int ip = mf * 8 + g * 2;
                        Lh[q * 28 + ip]     = (hh[1] << 16) | hh[0];
                        Lh[q * 28 + ip + 1] = (hh[3] << 16) | hh[2];
                        Ll[q * 28 + ip]     = (ll[1] << 16) | ll[0];
                        Ll[q * 28 + ip + 1] = (ll[3] << 16) | ll[2];
                    }
                }
            }
        }
    }
    __syncthreads();

    // ---- stage 2: 1x7 conv 49->49 + softmax + flow average (R6 kC body) ----
    const int pw  = wv << 5;                // 32 px per wave
    const int pix = pw + col;

    f32x4 acc[4][2];
    #pragma unroll
    for (int mf = 0; mf < 4; ++mf) {
        acc[mf][0] = (f32x4){0.f, 0.f, 0.f, 0.f};
        acc[mf][1] = (f32x4){0.f, 0.f, 0.f, 0.f};
    }

    #pragma unroll
    for (int c = 0; c < 13; ++c) {
        const int kg  = 4 * c + g;
        const int oct = (kg * 37) >> 8;
        const int t   = kg - 7 * oct;
        const int bq  = (pix + t) * 7 + oct;
        FragU bh0, bl0, bh1, bl1;
        bh0.q = Lh4[bq];        bl0.q = Ll4[bq];
        bh1.q = Lh4[bq + 112];  bl1.q = Ll4[bq + 112];
        #pragma unroll
        for (int mf = 0; mf < 4; ++mf) {
            FragU ah, al;
            ah.q = wpC[((c * 2 + 0) * 4 + mf) * 64 + lane];
            al.q = wpC[((c * 2 + 1) * 4 + mf) * 64 + lane];
            acc[mf][0] = __builtin_amdgcn_mfma_f32_16x16x32_bf16(ah.v, bh0.v, acc[mf][0], 0, 0, 0);
            acc[mf][0] = __builtin_amdgcn_mfma_f32_16x16x32_bf16(ah.v, bl0.v, acc[mf][0], 0, 0, 0);
            acc[mf][0] = __builtin_amdgcn_mfma_f32_16x16x32_bf16(al.v, bh0.v, acc[mf][0], 0, 0, 0);
            acc[mf][1] = __builtin_amdgcn_mfma_f32_16x16x32_bf16(ah.v, bh1.v, acc[mf][1], 0, 0, 0);
            acc[mf][1] = __builtin_amdgcn_mfma_f32_16x16x32_bf16(ah.v, bl1.v, acc[mf][1], 0, 0, 0);
            acc[mf][1] = __builtin_amdgcn_mfma_f32_16x16x32_bf16(al.v, bh1.v, acc[mf][1], 0, 0, 0);
        }
    }

    float bb[16];
    #pragma unroll
    for (int mf = 0; mf < 4; ++mf)
        #pragma unroll
        for (int r = 0; r < 4; ++r)
            bb[mf * 4 + r] = b2p[mf * 16 + g * 4 + r];

    #pragma unroll
    for (int mf = 0; mf < 4; ++mf)
        #pragma unroll
        for (int nf = 0; nf < 2; ++nf)
            #pragma unroll
            for (int r = 0; r < 4; ++r) {
                const float fv = acc[mf][nf][r] + bb[mf * 4 + r];
                acc[mf][nf][r] = fv * fv;
            }

    float pm[2];
    #pragma unroll
    for (int nf = 0; nf < 2; ++nf) {
        float m = acc[0][nf][0];
        #pragma unroll
        for (int mf = 0; mf < 4; ++mf)
            #pragma unroll
            for (int r = 0; r < 4; ++r)
                m = fminf(m, acc[mf][nf][r]);
        m = fminf(m, __shfl_xor(m, 16));
        m = fminf(m, __shfl_xor(m, 32));
        pm[nf] = m;
    }

    const float* fpx = flowp + (size_t)h * FP_W + (w0 + pw + col);
    const float* fpy = fpx + (size_t)FP_W * FP_W;
    float sx[2] = {0.f, 0.f};
    float sy[2] = {0.f, 0.f};
    float dv[2] = {0.f, 0.f};

    #pragma unroll
    for (int mf = 0; mf < 4; ++mf) {
        #pragma unroll
        for (int r = 0; r < 4; ++r) {
            const int ch = mf * 16 + g * 4 + r;
            int ki = (ch * 37) >> 8;
            int kj = ch - 7 * ki;
            ki = min(ki, 6);
            kj = min(kj, 6);
            const int off = ki * FP_W + kj;
            #pragma unroll
            for (int nf = 0; nf < 2; ++nf) {
                const float d = __expf(pm[nf] - acc[mf][nf][r]);
                dv[nf] += d;
                sx[nf] += d * fpx[off + nf * 16];
                sy[nf] += d * fpy[off + nf * 16];
            }
        }
    }

    #pragma unroll
    for (int nf = 0; nf < 2; ++nf) {
        float d = dv[nf], x = sx[nf], y = sy[nf];
        d += __shfl_xor(d, 16);  x += __shfl_xor(x, 16);  y += __shfl_xor(y, 16);
        d += __shfl_xor(d, 32);  x += __shfl_xor(x, 32);  y += __shfl_xor(y, 32);
        if (g == 0) {
            const int w = w0 + pw + nf * 16 + col;
            out[(size_t)h * WO + w]                     = x / d;
            out[(size_t)HO * WO + (size_t)h * WO + w]   = y / d;
        }
    }
}

// ---------------------------------------------------------------------------
extern "C" void kernel_launch(void* const* d_in, const int* in_sizes, int n_in,
                              void* d_out, int out_size, void* d_ws, size_t ws_size,
                              hipStream_t stream) {
    const float* reg_feat = (const float*)d_in[0];
    const float* flow     = (const float*)d_in[1];
    const float* wt       = (const float*)d_in[2];
    const float* bt       = (const float*)d_in[3];
    const float* w1       = (const float*)d_in[4];
    const float* b1       = (const float*)d_in[5];
    const float* w2       = (const float*)d_in[6];
    const float* b2       = (const float*)d_in[7];
    float* out = (float*)d_out;
    (void)in_sizes; (void)n_in; (void)out_size; (void)ws_size;

    float*    ws    = (float*)d_ws;
    uint4*    wpC   = (uint4*)(ws + OFF_WPC);
    float*    b2p   = ws + OFF_B2P;
    uint4*    wpB   = (uint4*)(ws + OFF_WPB);
    float*    b1p   = ws + OFF_B1P;
    uint4*    wpA   = (uint4*)(ws + OFF_WPA);
    unsigned* f0p   = (unsigned*)(ws + OFF_F0);
    unsigned* xpp   = (unsigned*)(ws + OFF_XPP);
    float*    flowp = ws + OFF_FLP;

    repack<<<26, 256, 0, stream>>>(wt, w1, b1, w2, b2, wpA, wpB, b1p, wpC, b2p);

    const int padBlocks = XP_W + (2 * FP_W * FP_W + 255) / 256;
    for (int b = 0; b < 4; ++b) {
        const float* xb  = reg_feat + (size_t)b * CI * HI * WI;
        const float* flb = flow     + (size_t)b * 2 * HO * WO;
        float*       ob  = out      + (size_t)b * 2 * HO * WO;
        kPP<<<padBlocks, 256, 0, stream>>>(xb, flb, xpp, flowp);
        kA<<<1024, 256, 0, stream>>>(xpp, wpA, bt, f0p);
        kBC<<<2048, 256, 0, stream>>>(f0p, wpB, b1p, wpC, b2p, flowp, ob);
    }
}

// Round 9
// 471.978 us; speedup vs baseline: 4.5542x; 1.0334x over previous
//
#include <hip/hip_runtime.h>

constexpr int HI = 256, WI = 256;   // reg_feat spatial
constexpr int HO = 512, WO = 512;   // upsampled spatial
constexpr int CI = 32;              // feat channels
constexpr int CK = 49;              // 7x7 unfold channels

// ---- ws layout (float offsets) --------------------------------------------
constexpr size_t OFF_WPC = 0;        // w2 frags: 13*2*4*64 uint4 = 26624 f32
constexpr size_t OFF_B2P = 26624;    // padded b2 [64]
constexpr size_t OFF_WPB = 26688;    // w1 frags: 7*2*4*64 uint4 = 14336 f32
constexpr size_t OFF_B1P = 41024;    // padded b1 [64]
constexpr size_t OFF_WPA = 41088;    // wt frags: 4cls*4tap*2s*2mf*64 uint4 = 16384 f32
constexpr size_t OFF_F0  = 57472;    // f0p u32 [512][512][32]
constexpr size_t OFF_XPP = OFF_F0 + (size_t)HO * WO * CI;      // xpp u32 [258][258][32]
constexpr size_t OFF_FLP = OFF_XPP + (size_t)258 * 258 * 32;   // flowp f32 [2][518][518]

constexpr int FP_W = 518;            // padded flow row (512 + 3 + 3)
constexpr int XP_W = 258;            // padded x row (256 + 1 + 1)

using bf16x8 = __attribute__((ext_vector_type(8))) short;
using f32x4  = __attribute__((ext_vector_type(4))) float;

__device__ inline unsigned bf_rne(float x) {           // fp32 -> bf16 bits (RNE)
    unsigned u = __float_as_uint(x);
    return (u + 0x7FFFu + ((u >> 16) & 1u)) >> 16;
}
__device__ inline unsigned pack_split(float v) {       // (hi<<16)|lo split-bf16
    const unsigned hi = bf_rne(v);
    const float vh = __uint_as_float(hi << 16);
    const unsigned lo = bf_rne(v - vh);
    return (hi << 16) | lo;
}

union FragU { uint4 q; bf16x8 v; unsigned u[4]; };

// v_perm selectors (validated R4-R8)
constexpr unsigned PERM_HI = 0x07060302u;
constexpr unsigned PERM_LO = 0x05040100u;

// ---------------------------------------------------------------------------
// kPP: fused padding kernel (unchanged R8).
// ---------------------------------------------------------------------------
__global__ void kPP(const float* __restrict__ x, const float* __restrict__ flow,
                    unsigned* __restrict__ xpp, float* __restrict__ flowp)
{
    const int bid = blockIdx.x;
    if (bid < XP_W) {
        const int yp = bid;
        const int y  = yp - 1;
        for (int xpc = threadIdx.x; xpc < XP_W; xpc += 256) {
            const int xc = xpc - 1;
            uint4* dst = reinterpret_cast<uint4*>(xpp + ((size_t)yp * XP_W + xpc) * 32);
            if ((unsigned)y < 256u && (unsigned)xc < 256u) {
                const float* src = x + y * 256 + xc;
                #pragma unroll
                for (int r = 0; r < 8; ++r) {
                    uint4 q;
                    q.x = pack_split(src[(size_t)(4 * r + 0) * 65536]);
                    q.y = pack_split(src[(size_t)(4 * r + 1) * 65536]);
                    q.z = pack_split(src[(size_t)(4 * r + 2) * 65536]);
                    q.w = pack_split(src[(size_t)(4 * r + 3) * 65536]);
                    dst[r] = q;
                }
            } else {
                #pragma unroll
                for (int r = 0; r < 8; ++r) dst[r] = make_uint4(0u, 0u, 0u, 0u);
            }
        }
    } else {
        const int idx = (bid - XP_W) * 256 + threadIdx.x;
        if (idx >= 2 * FP_W * FP_W) return;
        const int p  = idx / (FP_W * FP_W);
        const int q  = idx - p * (FP_W * FP_W);
        const int hh = q / FP_W;
        const int ww = q - hh * FP_W;
        float v = 0.f;
        const int hs = hh - 3, wsx = ww - 3;
        if ((unsigned)hs < (unsigned)HO && (unsigned)wsx < (unsigned)WO)
            v = flow[p * (HO * WO) + hs * WO + wsx];
        flowp[idx] = v;
    }
}

// ---------------------------------------------------------------------------
// repack (unchanged R8).
// ---------------------------------------------------------------------------
__global__ void repack(const float* __restrict__ wt,
                       const float* __restrict__ w1, const float* __restrict__ b1,
                       const float* __restrict__ w2, const float* __restrict__ b2,
                       uint4* __restrict__ wpA, uint4* __restrict__ wpB,
                       float* __restrict__ b1p, uint4* __restrict__ wpC,
                       float* __restrict__ b2p)
{
    const int j = blockIdx.x * 256 + threadIdx.x;
    if (j < 64) {
        b2p[j] = (j < CK) ? b2[j] : 1e18f;
        b1p[j] = (j < CK) ? b1[j] : 0.f;
    }
    if (j < 4 * 4 * 2 * 2 * 64) {           // kA
        const int lane = j & 63;
        const int mf   = (j >> 6) & 1;
        const int s    = (j >> 7) & 1;
        const int tap  = (j >> 8) & 3;
        const int cls  = j >> 10;
        const int ohpar = cls >> 1, par = cls & 1;
        const int a = tap >> 1, d = tap & 1;
        const int kh = (ohpar ? 0 : 1) + 2 * a;
        const int kw = (par ? 0 : 1) + 2 * d;
        const int o = mf * 16 + (lane & 15);
        unsigned b[8];
        #pragma unroll
        for (int jj = 0; jj < 8; ++jj) {
            const int i = (lane >> 4) * 8 + jj;
            const float v = wt[((i * 32 + o) * 4 + kh) * 4 + kw];
            const unsigned hi = bf_rne(v);
            b[jj] = (s == 0) ? hi : bf_rne(v - __uint_as_float(hi << 16));
        }
        uint4 q;
        q.x = (b[1] << 16) | b[0];
        q.y = (b[3] << 16) | b[2];
        q.z = (b[5] << 16) | b[4];
        q.w = (b[7] << 16) | b[6];
        wpA[j] = q;
    }
    if (j < 7 * 2 * 4 * 64) {               // stage-1: chunk t, k = i
        const int t    = j >> 9;
        const int s    = (j >> 8) & 1;
        const int mf   = (j >> 6) & 3;
        const int lane = j & 63;
        const int o = mf * 16 + (lane & 15);
        unsigned b[8];
        #pragma unroll
        for (int jj = 0; jj < 8; ++jj) {
            const int i = (lane >> 4) * 8 + jj;
            float v = (o < CK) ? w1[o * 224 + i * 7 + t] : 0.f;
            const unsigned hi = bf_rne(v);
            b[jj] = (s == 0) ? hi : bf_rne(v - __uint_as_float(hi << 16));
        }
        uint4 q;
        q.x = (b[1] << 16) | b[0];
        q.y = (b[3] << 16) | b[2];
        q.z = (b[5] << 16) | b[4];
        q.w = (b[7] << 16) | b[6];
        wpB[((t * 2 + s) * 4 + mf) * 64 + lane] = q;
    }
    if (j < 13 * 2 * 4 * 64) {              // stage-2: kg=4c+g -> (oct,t); i=oct*8+jj
        const int c    = j >> 9;
        const int s    = (j >> 8) & 1;
        const int mf   = (j >> 6) & 3;
        const int lane = j & 63;
        const int o   = mf * 16 + (lane & 15);
        const int kg  = 4 * c + (lane >> 4);
        const int oct = kg / 7;
        const int t   = kg - 7 * oct;
        unsigned b[8];
        #pragma unroll
        for (int jj = 0; jj < 8; ++jj) {
            const int i = oct * 8 + jj;
            float v = 0.f;
            if (kg < CK && o < CK && i < CK) v = w2[o * 343 + i * 7 + t];
            const unsigned hi = bf_rne(v);
            b[jj] = (s == 0) ? hi : bf_rne(v - __uint_as_float(hi << 16));
        }
        uint4 q;
        q.x = (b[1] << 16) | b[0];
        q.y = (b[3] << 16) | b[2];
        q.z = (b[5] << 16) | b[4];
        q.w = (b[7] << 16) | b[6];
        wpC[((c * 2 + s) * 4 + mf) * 64 + lane] = q;
    }
}

// ---------------------------------------------------------------------------
// kA: ConvTranspose2d(32,32,4,s=2,p=1) via split-bf16 MFMA (unchanged R8).
// ---------------------------------------------------------------------------
__global__ __launch_bounds__(256, 4)
void kA(const unsigned* __restrict__ xpp, const uint4* __restrict__ wpA,
        const float* __restrict__ bt, unsigned* __restrict__ f0p)
{
    __shared__ unsigned ep[4][64 * 36];

    const int tid  = threadIdx.x;
    const int oh   = blockIdx.x >> 1;
    const int half = blockIdx.x & 1;
    const int wv   = tid >> 6;
    const int lane = tid & 63;
    const int col  = lane & 15;
    const int g    = lane >> 4;
    const int par  = wv >> 1;
    const int n0   = half * 128 + (wv & 1) * 64;

    const int ohpar = oh & 1;
    const int kh0   = ohpar ? 0 : 1;
    const int ihA   = (oh + 1 - kh0) >> 1;
    const int cls   = ohpar * 2 + par;
    const int ioff  = par ? 2 : 1;

    f32x4 acc[2][4];
    #pragma unroll
    for (int mf = 0; mf < 2; ++mf)
        #pragma unroll
        for (int nf = 0; nf < 4; ++nf)
            acc[mf][nf] = (f32x4){0.f, 0.f, 0.f, 0.f};

    #pragma unroll
    for (int a = 0; a < 2; ++a) {
        const int rowbase = (ihA + 1 - a) * XP_W;
        #pragma unroll
        for (int d = 0; d < 2; ++d) {
            bf16x8 Bh[4], Bl[4];
            #pragma unroll
            for (int nf = 0; nf < 4; ++nf) {
                const size_t base =
                    ((size_t)(rowbase + n0 + nf * 16 + col + ioff - d)) * 32 + g * 8;
                const uint4 q0 = *reinterpret_cast<const uint4*>(xpp + base);
                const uint4 q1 = *reinterpret_cast<const uint4*>(xpp + base + 4);
                const unsigned u[8] = {q0.x, q0.y, q0.z, q0.w, q1.x, q1.y, q1.z, q1.w};
                FragU fh, fl;
                #pragma unroll
                for (int r = 0; r < 4; ++r) {
                    fh.u[r] = __builtin_amdgcn_perm(u[2 * r + 1], u[2 * r], PERM_HI);
                    fl.u[r] = __builtin_amdgcn_perm(u[2 * r + 1], u[2 * r], PERM_LO);
                }
                Bh[nf] = fh.v;
                Bl[nf] = fl.v;
            }
            const int tap = a * 2 + d;
            #pragma unroll
            for (int mf = 0; mf < 2; ++mf) {
                FragU ah, al;
                ah.q = wpA[(((cls * 4 + tap) * 2 + 0) * 2 + mf) * 64 + lane];
                al.q = wpA[(((cls * 4 + tap) * 2 + 1) * 2 + mf) * 64 + lane];
                #pragma unroll
                for (int nf = 0; nf < 4; ++nf) {
                    acc[mf][nf] = __builtin_amdgcn_mfma_f32_16x16x32_bf16(ah.v, Bh[nf], acc[mf][nf], 0, 0, 0);
                    acc[mf][nf] = __builtin_amdgcn_mfma_f32_16x16x32_bf16(ah.v, Bl[nf], acc[mf][nf], 0, 0, 0);
                    acc[mf][nf] = __builtin_amdgcn_mfma_f32_16x16x32_bf16(al.v, Bh[nf], acc[mf][nf], 0, 0, 0);
                }
            }
        }
    }

    unsigned* myep = ep[wv];
    #pragma unroll
    for (int mf = 0; mf < 2; ++mf)
        #pragma unroll
        for (int r = 0; r < 4; ++r) {
            const int ch = mf * 16 + g * 4 + r;
            const float bv = bt[ch];
            #pragma unroll
            for (int nf = 0; nf < 4; ++nf)
                myep[(nf * 16 + col) * 36 + ch] = pack_split(acc[mf][nf][r] + bv);
        }

    const int ow = 2 * (n0 + lane) + par;
    uint4* dst = reinterpret_cast<uint4*>(f0p + ((size_t)oh * WO + ow) * 32);
    const uint4* src = reinterpret_cast<const uint4*>(myep + lane * 36);
    #pragma unroll
    for (int u = 0; u < 8; ++u) dst[u] = src[u];
}

// ---------------------------------------------------------------------------
// kBC: FUSED stage B + stage C. Stage 1 unchanged (R8). Stage 2 restructured:
// wave wv computes ONLY mf=wv (16 channels) for ALL 128 px (nf=0..7) —
// A-frag (weight) traffic per block drops 4x (was: every wave re-read all
// 104 KB of wpC); B-frags come from the LDS port instead. Softmax epilogue
// is now cross-wave: per-pixel min and (dv,sx,sy) partials reduce via LDS.
// ---------------------------------------------------------------------------
__global__ __launch_bounds__(256, 4)
void kBC(const unsigned* __restrict__ f0p, const uint4* __restrict__ wpB,
         const float* __restrict__ b1p, const uint4* __restrict__ wpC,
         const float* __restrict__ b2p, const float* __restrict__ flowp,
         float* __restrict__ out)
{
    __shared__ uint4 Lh4[134 * 7];          // hi-plane, rows of 7 uint4 (56 ch)
    __shared__ uint4 Ll4[134 * 7];          // lo-plane
    __shared__ float gm[4][128];            // per-wave per-pixel min partials
    __shared__ float dvp[4][128];           // per-wave softmax partials
    __shared__ float sxp[4][128];
    __shared__ float syp[4][128];
    unsigned* Lh = reinterpret_cast<unsigned*>(Lh4);
    unsigned* Ll = reinterpret_cast<unsigned*>(Ll4);

    // bijective XCD swizzle: 2048 blocks = 8 XCDs x 256 contiguous
    const int bid = ((blockIdx.x & 7) << 8) + (blockIdx.x >> 3);
    const int h   = bid >> 2;
    const int w0  = (bid & 3) << 7;

    const int tid  = threadIdx.x;
    const int wv   = tid >> 6;
    const int lane = tid & 63;
    const int col  = lane & 15;
    const int g    = lane >> 4;

    // ---- stage 1: f1 row h, cols w0-3 .. w0+140 (9 frags of 16) ------------
    const int nfr = (wv == 3) ? 3 : 2;
    const int fid0 = wv, fid1 = wv + 4, fid2 = 8;

    f32x4 acc1[3][4];
    #pragma unroll
    for (int fi = 0; fi < 3; ++fi)
        #pragma unroll
        for (int mf = 0; mf < 4; ++mf)
            acc1[fi][mf] = (f32x4){0.f, 0.f, 0.f, 0.f};

    #pragma unroll
    for (int t = 0; t < 7; ++t) {
        const int hr = h + t - 3;
        if ((unsigned)hr < (unsigned)HO) {
            FragU ah[4], al[4];
            #pragma unroll
            for (int mf = 0; mf < 4; ++mf) {
                ah[mf].q = wpB[((t * 2 + 0) * 4 + mf) * 64 + lane];
                al[mf].q = wpB[((t * 2 + 1) * 4 + mf) * 64 + lane];
            }
            #pragma unroll
            for (int fi = 0; fi < 3; ++fi) {
                if (fi < nfr) {
                    const int f  = (fi == 0) ? fid0 : (fi == 1) ? fid1 : fid2;
                    const int wc = w0 - 3 + f * 16 + col;
                    const int wcc = min(max(wc, 0), WO - 1);
                    const bool valid = ((unsigned)wc < (unsigned)WO);
                    const size_t base = ((size_t)hr * WO + wcc) * 32 + g * 8;
                    uint4 q0 = *reinterpret_cast<const uint4*>(f0p + base);
                    uint4 q1 = *reinterpret_cast<const uint4*>(f0p + base + 4);
                    if (!valid) { q0 = make_uint4(0,0,0,0); q1 = make_uint4(0,0,0,0); }
                    const unsigned u[8] = {q0.x, q0.y, q0.z, q0.w, q1.x, q1.y, q1.z, q1.w};
                    FragU fh, fl;
                    #pragma unroll
                    for (int r = 0; r < 4; ++r) {
                        fh.u[r] = __builtin_amdgcn_perm(u[2 * r + 1], u[2 * r], PERM_HI);
                        fl.u[r] = __builtin_amdgcn_perm(u[2 * r + 1], u[2 * r], PERM_LO);
                    }
                    #pragma unroll
                    for (int mf = 0; mf < 4; ++mf) {
                        acc1[fi][mf] = __builtin_amdgcn_mfma_f32_16x16x32_bf16(ah[mf].v, fh.v, acc1[fi][mf], 0, 0, 0);
                        acc1[fi][mf] = __builtin_amdgcn_mfma_f32_16x16x32_bf16(ah[mf].v, fl.v, acc1[fi][mf], 0, 0, 0);
                        acc1[fi][mf] = __builtin_amdgcn_mfma_f32_16x16x32_bf16(al[mf].v, fh.v, acc1[fi][mf], 0, 0, 0);
                    }
                }
            }
        }
    }

    // write f1 row into transposed planes; out-of-image columns store ZERO.
    #pragma unroll
    for (int fi = 0; fi < 3; ++fi) {
        if (fi < nfr) {
            const int f = (fi == 0) ? fid0 : (fi == 1) ? fid1 : fid2;
            const int q = f * 16 + col;
            const int wc = w0 - 3 + q;
            const bool vcol = ((unsigned)wc < (unsigned)WO);
            if (q < 134) {
                #pragma unroll
                for (int mf = 0; mf < 4; ++mf) {
                    if (mf < 3 || g < 2) {          // ch 56..63 don't exist
                        const int chb = mf * 16 + g * 4;
                        unsigned hh[4], ll[4];
                        #pragma unroll
                        for (int r = 0; r < 4; ++r) {
                            const float v = vcol ? (acc1[fi][mf][r] + b1p[chb + r]) : 0.f;
                            hh[r] = bf_rne(v);
                            ll[r] = bf_rne(v - __uint_as_float(hh[r] << 16));
                        }
                        const int ip = mf * 8 + g * 2;
                        Lh[q * 28 + ip]     = (hh[1] << 16) | hh[0];
                        Lh[q * 28 + ip + 1] = (hh[3] << 16) | hh[2];
                        Ll[q * 28 + ip]     = (ll[1] << 16) | ll[0];
                        Ll[q * 28 + ip + 1] = (ll[3] << 16) | ll[2];
                    }
                }
            }
        }
    }
    __syncthreads();

    // ---- stage 2: wave wv = mf; all 128 px (nf=0..7) -----------------------
    const int mf2 = wv;
    f32x4 acc[8];
    #pragma unroll
    for (int nf = 0; nf < 8; ++nf)
        acc[nf] = (f32x4){0.f, 0.f, 0.f, 0.f};

    #pragma unroll
    for (int c = 0; c < 13; ++c) {
        const int kg  = 4 * c + g;
        const int oct = (kg * 37) >> 8;     // kg/7 for kg<=51
        const int t   = kg - 7 * oct;
        FragU ah, al;
        ah.q = wpC[((c * 2 + 0) * 4 + mf2) * 64 + lane];
        al.q = wpC[((c * 2 + 1) * 4 + mf2) * 64 + lane];
        const int bqb = (col + t) * 7 + oct;
        #pragma unroll
        for (int nf = 0; nf < 8; ++nf) {
            FragU bh, bl;
            bh.q = Lh4[bqb + nf * 112];     // +16 px * 7 uint4
            bl.q = Ll4[bqb + nf * 112];
            acc[nf] = __builtin_amdgcn_mfma_f32_16x16x32_bf16(ah.v, bh.v, acc[nf], 0, 0, 0);
            acc[nf] = __builtin_amdgcn_mfma_f32_16x16x32_bf16(ah.v, bl.v, acc[nf], 0, 0, 0);
            acc[nf] = __builtin_amdgcn_mfma_f32_16x16x32_bf16(al.v, bh.v, acc[nf], 0, 0, 0);
        }
    }

    // ---- epilogue: sq, cross-wave min, exp-weighted flow average -----------
    float bb2[4];
    #pragma unroll
    for (int r = 0; r < 4; ++r)
        bb2[r] = b2p[mf2 * 16 + g * 4 + r];

    #pragma unroll
    for (int nf = 0; nf < 8; ++nf)
        #pragma unroll
        for (int r = 0; r < 4; ++r) {
            const float fv = acc[nf][r] + bb2[r];
            acc[nf][r] = fv * fv;
        }

    #pragma unroll
    for (int nf = 0; nf < 8; ++nf) {
        float m = fminf(fminf(acc[nf][0], acc[nf][1]), fminf(acc[nf][2], acc[nf][3]));
        m = fminf(m, __shfl_xor(m, 16));
        m = fminf(m, __shfl_xor(m, 32));
        if (lane < 16) gm[wv][nf * 16 + lane] = m;
    }
    __syncthreads();

    float M[8];
    #pragma unroll
    for (int nf = 0; nf < 8; ++nf)
        M[nf] = fminf(fminf(gm[0][nf * 16 + col], gm[1][nf * 16 + col]),
                      fminf(gm[2][nf * 16 + col], gm[3][nf * 16 + col]));

    const float* fpx = flowp + (size_t)h * FP_W + (w0 + col);
    const float* fpy = fpx + (size_t)FP_W * FP_W;
    float dv[8], sx[8], sy[8];
    #pragma unroll
    for (int nf = 0; nf < 8; ++nf) { dv[nf] = 0.f; sx[nf] = 0.f; sy[nf] = 0.f; }

    #pragma unroll
    for (int r = 0; r < 4; ++r) {
        const int ch = mf2 * 16 + g * 4 + r;
        int ki = (ch * 37) >> 8;            // floor(ch/7) for ch<64
        int kj = ch - 7 * ki;
        ki = min(ki, 6);                    // pad channels: d==0, clamp for safety
        kj = min(kj, 6);
        const int off = ki * FP_W + kj;
        #pragma unroll
        for (int nf = 0; nf < 8; ++nf) {
            const float d = __expf(M[nf] - acc[nf][r]);
            dv[nf] += d;
            sx[nf] += d * fpx[off + nf * 16];
            sy[nf] += d * fpy[off + nf * 16];
        }
    }

    #pragma unroll
    for (int nf = 0; nf < 8; ++nf) {
        float d = dv[nf], x = sx[nf], y = sy[nf];
        d += __shfl_xor(d, 16);  x += __shfl_xor(x, 16);  y += __shfl_xor(y, 16);
        d += __shfl_xor(d, 32);  x += __shfl_xor(x, 32);  y += __shfl_xor(y, 32);
        if (lane < 16) {
            dvp[wv][nf * 16 + lane] = d;
            sxp[wv][nf * 16 + lane] = x;
            syp[wv][nf * 16 + lane] = y;
        }
    }
    __syncthreads();

    if (tid < 128) {
        const float D = dvp[0][tid] + dvp[1][tid] + dvp[2][tid] + dvp[3][tid];
        const float X = sxp[0][tid] + sxp[1][tid] + sxp[2][tid] + sxp[3][tid];
        const float Y = syp[0][tid] + syp[1][tid] + syp[2][tid] + syp[3][tid];
        const int w = w0 + tid;
        out[(size_t)h * WO + w]                   = X / D;
        out[(size_t)HO * WO + (size_t)h * WO + w] = Y / D;
    }
}

// ---------------------------------------------------------------------------
extern "C" void kernel_launch(void* const* d_in, const int* in_sizes, int n_in,
                              void* d_out, int out_size, void* d_ws, size_t ws_size,
                              hipStream_t stream) {
    const float* reg_feat = (const float*)d_in[0];
    const float* flow     = (const float*)d_in[1];
    const float* wt       = (const float*)d_in[2];
    const float* bt       = (const float*)d_in[3];
    const float* w1       = (const float*)d_in[4];
    const float* b1       = (const float*)d_in[5];
    const float* w2       = (const float*)d_in[6];
    const float* b2       = (const float*)d_in[7];
    float* out = (float*)d_out;
    (void)in_sizes; (void)n_in; (void)out_size; (void)ws_size;

    float*    ws    = (float*)d_ws;
    uint4*    wpC   = (uint4*)(ws + OFF_WPC);
    float*    b2p   = ws + OFF_B2P;
    uint4*    wpB   = (uint4*)(ws + OFF_WPB);
    float*    b1p   = ws + OFF_B1P;
    uint4*    wpA   = (uint4*)(ws + OFF_WPA);
    unsigned* f0p   = (unsigned*)(ws + OFF_F0);
    unsigned* xpp   = (unsigned*)(ws + OFF_XPP);
    float*    flowp = ws + OFF_FLP;

    repack<<<26, 256, 0, stream>>>(wt, w1, b1, w2, b2, wpA, wpB, b1p, wpC, b2p);

    const int padBlocks = XP_W + (2 * FP_W * FP_W + 255) / 256;
    for (int b = 0; b < 4; ++b) {
        const float* xb  = reg_feat + (size_t)b * CI * HI * WI;
        const float* flb = flow     + (size_t)b * 2 * HO * WO;
        float*       ob  = out      + (size_t)b * 2 * HO * WO;
        kPP<<<padBlocks, 256, 0, stream>>>(xb, flb, xpp, flowp);
        kA<<<1024, 256, 0, stream>>>(xpp, wpA, bt, f0p);
        kBC<<<2048, 256, 0, stream>>>(f0p, wpB, b1p, wpC, b2p, flowp, ob);
    }
}

// Round 11
// 471.121 us; speedup vs baseline: 4.5625x; 1.0018x over previous
//
#include <hip/hip_runtime.h>

constexpr int HI = 256, WI = 256;   // reg_feat spatial
constexpr int HO = 512, WO = 512;   // upsampled spatial
constexpr int CI = 32;              // feat channels
constexpr int CK = 49;              // 7x7 unfold channels

// ---- ws layout (float offsets) --------------------------------------------
constexpr size_t OFF_WPC = 0;        // w2 frags: 13*2*4*64 uint4 = 26624 f32
constexpr size_t OFF_B2P = 26624;    // padded b2 [64]
constexpr size_t OFF_WPB = 26688;    // w1 frags: 7*2*4*64 uint4 = 14336 f32
constexpr size_t OFF_B1P = 41024;    // padded b1 [64]
constexpr size_t OFF_WPA = 41088;    // wt frags: 4cls*4tap*2s*2mf*64 uint4 = 16384 f32
constexpr size_t OFF_F0  = 57472;    // f0p u32 [512][512][32]
constexpr size_t OFF_XPP = OFF_F0 + (size_t)HO * WO * CI;      // xpp u32 [258][258][32]
constexpr size_t OFF_FLP = OFF_XPP + (size_t)258 * 258 * 32;   // flowp f32 [2][518][518]

constexpr int FP_W = 518;            // padded flow row (512 + 3 + 3)
constexpr int XP_W = 258;            // padded x row (256 + 1 + 1)

using bf16x8 = __attribute__((ext_vector_type(8))) short;
using f32x4  = __attribute__((ext_vector_type(4))) float;

__device__ inline unsigned bf_rne(float x) {           // fp32 -> bf16 bits (RNE)
    unsigned u = __float_as_uint(x);
    return (u + 0x7FFFu + ((u >> 16) & 1u)) >> 16;
}
__device__ inline unsigned pack_split(float v) {       // (hi<<16)|lo split-bf16
    const unsigned hi = bf_rne(v);
    const float vh = __uint_as_float(hi << 16);
    const unsigned lo = bf_rne(v - vh);
    return (hi << 16) | lo;
}

union FragU { uint4 q; bf16x8 v; unsigned u[4]; };

// v_perm selectors (validated R4-R9)
constexpr unsigned PERM_HI = 0x07060302u;
constexpr unsigned PERM_LO = 0x05040100u;

// ---------------------------------------------------------------------------
// kPP: fused padding kernel (unchanged R8/R9).
// ---------------------------------------------------------------------------
__global__ void kPP(const float* __restrict__ x, const float* __restrict__ flow,
                    unsigned* __restrict__ xpp, float* __restrict__ flowp)
{
    const int bid = blockIdx.x;
    if (bid < XP_W) {
        const int yp = bid;
        const int y  = yp - 1;
        for (int xpc = threadIdx.x; xpc < XP_W; xpc += 256) {
            const int xc = xpc - 1;
            uint4* dst = reinterpret_cast<uint4*>(xpp + ((size_t)yp * XP_W + xpc) * 32);
            if ((unsigned)y < 256u && (unsigned)xc < 256u) {
                const float* src = x + y * 256 + xc;
                #pragma unroll
                for (int r = 0; r < 8; ++r) {
                    uint4 q;
                    q.x = pack_split(src[(size_t)(4 * r + 0) * 65536]);
                    q.y = pack_split(src[(size_t)(4 * r + 1) * 65536]);
                    q.z = pack_split(src[(size_t)(4 * r + 2) * 65536]);
                    q.w = pack_split(src[(size_t)(4 * r + 3) * 65536]);
                    dst[r] = q;
                }
            } else {
                #pragma unroll
                for (int r = 0; r < 8; ++r) dst[r] = make_uint4(0u, 0u, 0u, 0u);
            }
        }
    } else {
        const int idx = (bid - XP_W) * 256 + threadIdx.x;
        if (idx >= 2 * FP_W * FP_W) return;
        const int p  = idx / (FP_W * FP_W);
        const int q  = idx - p * (FP_W * FP_W);
        const int hh = q / FP_W;
        const int ww = q - hh * FP_W;
        float v = 0.f;
        const int hs = hh - 3, wsx = ww - 3;
        if ((unsigned)hs < (unsigned)HO && (unsigned)wsx < (unsigned)WO)
            v = flow[p * (HO * WO) + hs * WO + wsx];
        flowp[idx] = v;
    }
}

// ---------------------------------------------------------------------------
// repack (unchanged R8/R9).
// ---------------------------------------------------------------------------
__global__ void repack(const float* __restrict__ wt,
                       const float* __restrict__ w1, const float* __restrict__ b1,
                       const float* __restrict__ w2, const float* __restrict__ b2,
                       uint4* __restrict__ wpA, uint4* __restrict__ wpB,
                       float* __restrict__ b1p, uint4* __restrict__ wpC,
                       float* __restrict__ b2p)
{
    const int j = blockIdx.x * 256 + threadIdx.x;
    if (j < 64) {
        b2p[j] = (j < CK) ? b2[j] : 1e18f;
        b1p[j] = (j < CK) ? b1[j] : 0.f;
    }
    if (j < 4 * 4 * 2 * 2 * 64) {           // kA
        const int lane = j & 63;
        const int mf   = (j >> 6) & 1;
        const int s    = (j >> 7) & 1;
        const int tap  = (j >> 8) & 3;
        const int cls  = j >> 10;
        const int ohpar = cls >> 1, par = cls & 1;
        const int a = tap >> 1, d = tap & 1;
        const int kh = (ohpar ? 0 : 1) + 2 * a;
        const int kw = (par ? 0 : 1) + 2 * d;
        const int o = mf * 16 + (lane & 15);
        unsigned b[8];
        #pragma unroll
        for (int jj = 0; jj < 8; ++jj) {
            const int i = (lane >> 4) * 8 + jj;
            const float v = wt[((i * 32 + o) * 4 + kh) * 4 + kw];
            const unsigned hi = bf_rne(v);
            b[jj] = (s == 0) ? hi : bf_rne(v - __uint_as_float(hi << 16));
        }
        uint4 q;
        q.x = (b[1] << 16) | b[0];
        q.y = (b[3] << 16) | b[2];
        q.z = (b[5] << 16) | b[4];
        q.w = (b[7] << 16) | b[6];
        wpA[j] = q;
    }
    if (j < 7 * 2 * 4 * 64) {               // stage-1: chunk t, k = i
        const int t    = j >> 9;
        const int s    = (j >> 8) & 1;
        const int mf   = (j >> 6) & 3;
        const int lane = j & 63;
        const int o = mf * 16 + (lane & 15);
        unsigned b[8];
        #pragma unroll
        for (int jj = 0; jj < 8; ++jj) {
            const int i = (lane >> 4) * 8 + jj;
            float v = (o < CK) ? w1[o * 224 + i * 7 + t] : 0.f;
            const unsigned hi = bf_rne(v);
            b[jj] = (s == 0) ? hi : bf_rne(v - __uint_as_float(hi << 16));
        }
        uint4 q;
        q.x = (b[1] << 16) | b[0];
        q.y = (b[3] << 16) | b[2];
        q.z = (b[5] << 16) | b[4];
        q.w = (b[7] << 16) | b[6];
        wpB[((t * 2 + s) * 4 + mf) * 64 + lane] = q;
    }
    if (j < 13 * 2 * 4 * 64) {              // stage-2: kg=4c+g -> (oct,t); i=oct*8+jj
        const int c    = j >> 9;
        const int s    = (j >> 8) & 1;
        const int mf   = (j >> 6) & 3;
        const int lane = j & 63;
        const int o   = mf * 16 + (lane & 15);
        const int kg  = 4 * c + (lane >> 4);
        const int oct = kg / 7;
        const int t   = kg - 7 * oct;
        unsigned b[8];
        #pragma unroll
        for (int jj = 0; jj < 8; ++jj) {
            const int i = oct * 8 + jj;
            float v = 0.f;
            if (kg < CK && o < CK && i < CK) v = w2[o * 343 + i * 7 + t];
            const unsigned hi = bf_rne(v);
            b[jj] = (s == 0) ? hi : bf_rne(v - __uint_as_float(hi << 16));
        }
        uint4 q;
        q.x = (b[1] << 16) | b[0];
        q.y = (b[3] << 16) | b[2];
        q.z = (b[5] << 16) | b[4];
        q.w = (b[7] << 16) | b[6];
        wpC[((c * 2 + s) * 4 + mf) * 64 + lane] = q;
    }
}

// ---------------------------------------------------------------------------
// kA: ConvTranspose2d(32,32,4,s=2,p=1) via split-bf16 MFMA (unchanged R8/R9).
// ---------------------------------------------------------------------------
__global__ __launch_bounds__(256, 4)
void kA(const unsigned* __restrict__ xpp, const uint4* __restrict__ wpA,
        const float* __restrict__ bt, unsigned* __restrict__ f0p)
{
    __shared__ unsigned ep[4][64 * 36];

    const int tid  = threadIdx.x;
    const int oh   = blockIdx.x >> 1;
    const int half = blockIdx.x & 1;
    const int wv   = tid >> 6;
    const int lane = tid & 63;
    const int col  = lane & 15;
    const int g    = lane >> 4;
    const int par  = wv >> 1;
    const int n0   = half * 128 + (wv & 1) * 64;

    const int ohpar = oh & 1;
    const int kh0   = ohpar ? 0 : 1;
    const int ihA   = (oh + 1 - kh0) >> 1;
    const int cls   = ohpar * 2 + par;
    const int ioff  = par ? 2 : 1;

    f32x4 acc[2][4];
    #pragma unroll
    for (int mf = 0; mf < 2; ++mf)
        #pragma unroll
        for (int nf = 0; nf < 4; ++nf)
            acc[mf][nf] = (f32x4){0.f, 0.f, 0.f, 0.f};

    #pragma unroll
    for (int a = 0; a < 2; ++a) {
        const int rowbase = (ihA + 1 - a) * XP_W;
        #pragma unroll
        for (int d = 0; d < 2; ++d) {
            bf16x8 Bh[4], Bl[4];
            #pragma unroll
            for (int nf = 0; nf < 4; ++nf) {
                const size_t base =
                    ((size_t)(rowbase + n0 + nf * 16 + col + ioff - d)) * 32 + g * 8;
                const uint4 q0 = *reinterpret_cast<const uint4*>(xpp + base);
                const uint4 q1 = *reinterpret_cast<const uint4*>(xpp + base + 4);
                const unsigned u[8] = {q0.x, q0.y, q0.z, q0.w, q1.x, q1.y, q1.z, q1.w};
                FragU fh, fl;
                #pragma unroll
                for (int r = 0; r < 4; ++r) {
                    fh.u[r] = __builtin_amdgcn_perm(u[2 * r + 1], u[2 * r], PERM_HI);
                    fl.u[r] = __builtin_amdgcn_perm(u[2 * r + 1], u[2 * r], PERM_LO);
                }
                Bh[nf] = fh.v;
                Bl[nf] = fl.v;
            }
            const int tap = a * 2 + d;
            #pragma unroll
            for (int mf = 0; mf < 2; ++mf) {
                FragU ah, al;
                ah.q = wpA[(((cls * 4 + tap) * 2 + 0) * 2 + mf) * 64 + lane];
                al.q = wpA[(((cls * 4 + tap) * 2 + 1) * 2 + mf) * 64 + lane];
                #pragma unroll
                for (int nf = 0; nf < 4; ++nf) {
                    acc[mf][nf] = __builtin_amdgcn_mfma_f32_16x16x32_bf16(ah.v, Bh[nf], acc[mf][nf], 0, 0, 0);
                    acc[mf][nf] = __builtin_amdgcn_mfma_f32_16x16x32_bf16(ah.v, Bl[nf], acc[mf][nf], 0, 0, 0);
                    acc[mf][nf] = __builtin_amdgcn_mfma_f32_16x16x32_bf16(al.v, Bh[nf], acc[mf][nf], 0, 0, 0);
                }
            }
        }
    }

    unsigned* myep = ep[wv];
    #pragma unroll
    for (int mf = 0; mf < 2; ++mf)
        #pragma unroll
        for (int r = 0; r < 4; ++r) {
            const int ch = mf * 16 + g * 4 + r;
            const float bv = bt[ch];
            #pragma unroll
            for (int nf = 0; nf < 4; ++nf)
                myep[(nf * 16 + col) * 36 + ch] = pack_split(acc[mf][nf][r] + bv);
        }

    const int ow = 2 * (n0 + lane) + par;
    uint4* dst = reinterpret_cast<uint4*>(f0p + ((size_t)oh * WO + ow) * 32);
    const uint4* src = reinterpret_cast<const uint4*>(myep + lane * 36);
    #pragma unroll
    for (int u = 0; u < 8; ++u) dst[u] = src[u];
}

// ---------------------------------------------------------------------------
// kBC: FUSED stage B + stage C — EXACT R9 version (known-good under graph
// replay). Stage 2: wave wv computes ONLY mf=wv (16 channels) for ALL 128 px.
// Softmax epilogue cross-wave via SEPARATE LDS arrays (R10's aliased-LDS
// epilogue raced under replay; reverted).
// ---------------------------------------------------------------------------
__global__ __launch_bounds__(256, 4)
void kBC(const unsigned* __restrict__ f0p, const uint4* __restrict__ wpB,
         const float* __restrict__ b1p, const uint4* __restrict__ wpC,
         const float* __restrict__ b2p, const float* __restrict__ flowp,
         float* __restrict__ out)
{
    __shared__ uint4 Lh4[134 * 7];          // hi-plane, rows of 7 uint4 (56 ch)
    __shared__ uint4 Ll4[134 * 7];          // lo-plane
    __shared__ float gm[4][128];            // per-wave per-pixel min partials
    __shared__ float dvp[4][128];           // per-wave softmax partials
    __shared__ float sxp[4][128];
    __shared__ float syp[4][128];
    unsigned* Lh = reinterpret_cast<unsigned*>(Lh4);
    unsigned* Ll = reinterpret_cast<unsigned*>(Ll4);

    // bijective XCD swizzle: 2048 blocks = 8 XCDs x 256 contiguous
    const int bid = ((blockIdx.x & 7) << 8) + (blockIdx.x >> 3);
    const int h   = bid >> 2;
    const int w0  = (bid & 3) << 7;

    const int tid  = threadIdx.x;
    const int wv   = tid >> 6;
    const int lane = tid & 63;
    const int col  = lane & 15;
    const int g    = lane >> 4;

    // ---- stage 1: f1 row h, cols w0-3 .. w0+140 (9 frags of 16) ------------
    const int nfr = (wv == 3) ? 3 : 2;
    const int fid0 = wv, fid1 = wv + 4, fid2 = 8;

    f32x4 acc1[3][4];
    #pragma unroll
    for (int fi = 0; fi < 3; ++fi)
        #pragma unroll
        for (int mf = 0; mf < 4; ++mf)
            acc1[fi][mf] = (f32x4){0.f, 0.f, 0.f, 0.f};

    #pragma unroll
    for (int t = 0; t < 7; ++t) {
        const int hr = h + t - 3;
        if ((unsigned)hr < (unsigned)HO) {
            FragU ah[4], al[4];
            #pragma unroll
            for (int mf = 0; mf < 4; ++mf) {
                ah[mf].q = wpB[((t * 2 + 0) * 4 + mf) * 64 + lane];
                al[mf].q = wpB[((t * 2 + 1) * 4 + mf) * 64 + lane];
            }
            #pragma unroll
            for (int fi = 0; fi < 3; ++fi) {
                if (fi < nfr) {
                    const int f  = (fi == 0) ? fid0 : (fi == 1) ? fid1 : fid2;
                    const int wc = w0 - 3 + f * 16 + col;
                    const int wcc = min(max(wc, 0), WO - 1);
                    const bool valid = ((unsigned)wc < (unsigned)WO);
                    const size_t base = ((size_t)hr * WO + wcc) * 32 + g * 8;
                    uint4 q0 = *reinterpret_cast<const uint4*>(f0p + base);
                    uint4 q1 = *reinterpret_cast<const uint4*>(f0p + base + 4);
                    if (!valid) { q0 = make_uint4(0,0,0,0); q1 = make_uint4(0,0,0,0); }
                    const unsigned u[8] = {q0.x, q0.y, q0.z, q0.w, q1.x, q1.y, q1.z, q1.w};
                    FragU fh, fl;
                    #pragma unroll
                    for (int r = 0; r < 4; ++r) {
                        fh.u[r] = __builtin_amdgcn_perm(u[2 * r + 1], u[2 * r], PERM_HI);
                        fl.u[r] = __builtin_amdgcn_perm(u[2 * r + 1], u[2 * r], PERM_LO);
                    }
                    #pragma unroll
                    for (int mf = 0; mf < 4; ++mf) {
                        acc1[fi][mf] = __builtin_amdgcn_mfma_f32_16x16x32_bf16(ah[mf].v, fh.v, acc1[fi][mf], 0, 0, 0);
                        acc1[fi][mf] = __builtin_amdgcn_mfma_f32_16x16x32_bf16(ah[mf].v, fl.v, acc1[fi][mf], 0, 0, 0);
                        acc1[fi][mf] = __builtin_amdgcn_mfma_f32_16x16x32_bf16(al[mf].v, fh.v, acc1[fi][mf], 0, 0, 0);
                    }
                }
            }
        }
    }

    // write f1 row into transposed planes; out-of-image columns store ZERO.
    #pragma unroll
    for (int fi = 0; fi < 3; ++fi) {
        if (fi < nfr) {
            const int f = (fi == 0) ? fid0 : (fi == 1) ? fid1 : fid2;
            const int q = f * 16 + col;
            const int wc = w0 - 3 + q;
            const bool vcol = ((unsigned)wc < (unsigned)WO);
            if (q < 134) {
                #pragma unroll
                for (int mf = 0; mf < 4; ++mf) {
                    if (mf < 3 || g < 2) {          // ch 56..63 don't exist
                        const int chb = mf * 16 + g * 4;
                        unsigned hh[4], ll[4];
                        #pragma unroll
                        for (int r = 0; r < 4; ++r) {
                            const float v = vcol ? (acc1[fi][mf][r] + b1p[chb + r]) : 0.f;
                            hh[r] = bf_rne(v);
                            ll[r] = bf_rne(v - __uint_as_float(hh[r] << 16));
                        }
                        const int ip = mf * 8 + g * 2;
                        Lh[q * 28 + ip]     = (hh[1] << 16) | hh[0];
                        Lh[q * 28 + ip + 1] = (hh[3] << 16) | hh[2];
                        Ll[q * 28 + ip]     = (ll[1] << 16) | ll[0];
                        Ll[q * 28 + ip + 1] = (ll[3] << 16) | ll[2];
                    }
                }
            }
        }
    }
    __syncthreads();

    // ---- stage 2: wave wv = mf; all 128 px (nf=0..7) -----------------------
    const int mf2 = wv;
    f32x4 acc[8];
    #pragma unroll
    for (int nf = 0; nf < 8; ++nf)
        acc[nf] = (f32x4){0.f, 0.f, 0.f, 0.f};

    #pragma unroll
    for (int c = 0; c < 13; ++c) {
        const int kg  = 4 * c + g;
        const int oct = (kg * 37) >> 8;     // kg/7 for kg<=51
        const int t   = kg - 7 * oct;
        FragU ah, al;
        ah.q = wpC[((c * 2 + 0) * 4 + mf2) * 64 + lane];
        al.q = wpC[((c * 2 + 1) * 4 + mf2) * 64 + lane];
        const int bqb = (col + t) * 7 + oct;
        #pragma unroll
        for (int nf = 0; nf < 8; ++nf) {
            FragU bh, bl;
            bh.q = Lh4[bqb + nf * 112];     // +16 px * 7 uint4
            bl.q = Ll4[bqb + nf * 112];
            acc[nf] = __builtin_amdgcn_mfma_f32_16x16x32_bf16(ah.v, bh.v, acc[nf], 0, 0, 0);
            acc[nf] = __builtin_amdgcn_mfma_f32_16x16x32_bf16(ah.v, bl.v, acc[nf], 0, 0, 0);
            acc[nf] = __builtin_amdgcn_mfma_f32_16x16x32_bf16(al.v, bh.v, acc[nf], 0, 0, 0);
        }
    }

    // ---- epilogue: sq, cross-wave min, exp-weighted flow average -----------
    float bb2[4];
    #pragma unroll
    for (int r = 0; r < 4; ++r)
        bb2[r] = b2p[mf2 * 16 + g * 4 + r];

    #pragma unroll
    for (int nf = 0; nf < 8; ++nf)
        #pragma unroll
        for (int r = 0; r < 4; ++r) {
            const float fv = acc[nf][r] + bb2[r];
            acc[nf][r] = fv * fv;
        }

    #pragma unroll
    for (int nf = 0; nf < 8; ++nf) {
        float m = fminf(fminf(acc[nf][0], acc[nf][1]), fminf(acc[nf][2], acc[nf][3]));
        m = fminf(m, __shfl_xor(m, 16));
        m = fminf(m, __shfl_xor(m, 32));
        if (lane < 16) gm[wv][nf * 16 + lane] = m;
    }
    __syncthreads();

    float M[8];
    #pragma unroll
    for (int nf = 0; nf < 8; ++nf)
        M[nf] = fminf(fminf(gm[0][nf * 16 + col], gm[1][nf * 16 + col]),
                      fminf(gm[2][nf * 16 + col], gm[3][nf * 16 + col]));

    const float* fpx = flowp + (size_t)h * FP_W + (w0 + col);
    const float* fpy = fpx + (size_t)FP_W * FP_W;
    float dv[8], sx[8], sy[8];
    #pragma unroll
    for (int nf = 0; nf < 8; ++nf) { dv[nf] = 0.f; sx[nf] = 0.f; sy[nf] = 0.f; }

    #pragma unroll
    for (int r = 0; r < 4; ++r) {
        const int ch = mf2 * 16 + g * 4 + r;
        int ki = (ch * 37) >> 8;            // floor(ch/7) for ch<64
        int kj = ch - 7 * ki;
        ki = min(ki, 6);                    // pad channels: d==0, clamp for safety
        kj = min(kj, 6);
        const int off = ki * FP_W + kj;
        #pragma unroll
        for (int nf = 0; nf < 8; ++nf) {
            const float d = __expf(M[nf] - acc[nf][r]);
            dv[nf] += d;
            sx[nf] += d * fpx[off + nf * 16];
            sy[nf] += d * fpy[off + nf * 16];
        }
    }

    #pragma unroll
    for (int nf = 0; nf < 8; ++nf) {
        float d = dv[nf], x = sx[nf], y = sy[nf];
        d += __shfl_xor(d, 16);  x += __shfl_xor(x, 16);  y += __shfl_xor(y, 16);
        d += __shfl_xor(d, 32);  x += __shfl_xor(x, 32);  y += __shfl_xor(y, 32);
        if (lane < 16) {
            dvp[wv][nf * 16 + lane] = d;
            sxp[wv][nf * 16 + lane] = x;
            syp[wv][nf * 16 + lane] = y;
        }
    }
    __syncthreads();

    if (tid < 128) {
        const float D = dvp[0][tid] + dvp[1][tid] + dvp[2][tid] + dvp[3][tid];
        const float X = sxp[0][tid] + sxp[1][tid] + sxp[2][tid] + sxp[3][tid];
        const float Y = syp[0][tid] + syp[1][tid] + syp[2][tid] + syp[3][tid];
        const int w = w0 + tid;
        out[(size_t)h * WO + w]                   = X / D;
        out[(size_t)HO * WO + (size_t)h * WO + w] = Y / D;
    }
}

// ---------------------------------------------------------------------------
extern "C" void kernel_launch(void* const* d_in, const int* in_sizes, int n_in,
                              void* d_out, int out_size, void* d_ws, size_t ws_size,
                              hipStream_t stream) {
    const float* reg_feat = (const float*)d_in[0];
    const float* flow     = (const float*)d_in[1];
    const float* wt       = (const float*)d_in[2];
    const float* bt       = (const float*)d_in[3];
    const float* w1       = (const float*)d_in[4];
    const float* b1       = (const float*)d_in[5];
    const float* w2       = (const float*)d_in[6];
    const float* b2       = (const float*)d_in[7];
    float* out = (float*)d_out;
    (void)in_sizes; (void)n_in; (void)out_size; (void)ws_size;

    float*    ws    = (float*)d_ws;
    uint4*    wpC   = (uint4*)(ws + OFF_WPC);
    float*    b2p   = ws + OFF_B2P;
    uint4*    wpB   = (uint4*)(ws + OFF_WPB);
    float*    b1p   = ws + OFF_B1P;
    uint4*    wpA   = (uint4*)(ws + OFF_WPA);
    unsigned* f0p   = (unsigned*)(ws + OFF_F0);
    unsigned* xpp   = (unsigned*)(ws + OFF_XPP);
    float*    flowp = ws + OFF_FLP;

    repack<<<26, 256, 0, stream>>>(wt, w1, b1, w2, b2, wpA, wpB, b1p, wpC, b2p);

    const int padBlocks = XP_W + (2 * FP_W * FP_W + 255) / 256;
    for (int b = 0; b < 4; ++b) {
        const float* xb  = reg_feat + (size_t)b * CI * HI * WI;
        const float* flb = flow     + (size_t)b * 2 * HO * WO;
        float*       ob  = out      + (size_t)b * 2 * HO * WO;
        kPP<<<padBlocks, 256, 0, stream>>>(xb, flb, xpp, flowp);
        kA<<<1024, 256, 0, stream>>>(xpp, wpA, bt, f0p);
        kBC<<<2048, 256, 0, stream>>>(f0p, wpB, b1p, wpC, b2p, flowp, ob);
    }
}